// Round 4
// baseline (139.197 us; speedup 1.0000x reference)
//
#include <hip/hip_runtime.h>
#include <hip/hip_bf16.h>

#define B_ 8
#define S_ 2048
#define D_ 256
#define U_ 128
#define BS_ (B_*S_)

using bf16 = __hip_bfloat16;
typedef __attribute__((ext_vector_type(8))) __bf16 bf8v;      // MFMA A/B frag (4 VGPR)
typedef __attribute__((ext_vector_type(4))) float f4v;        // 16x16 C/D frag
typedef __attribute__((ext_vector_type(16))) float f16v;      // 32x32 C/D frag
typedef __attribute__((ext_vector_type(4))) float float4v;
typedef __attribute__((ext_vector_type(4))) unsigned short us4;
typedef __attribute__((ext_vector_type(4))) unsigned int u4v;

#define MFMA16(a,b,c) __builtin_amdgcn_mfma_f32_16x16x32_bf16((a),(b),(c),0,0,0)
#define MFMA32(a,b,c) __builtin_amdgcn_mfma_f32_32x32x16_bf16((a),(b),(c),0,0,0)

__device__ __forceinline__ unsigned short f2bits(float f){
  return __builtin_bit_cast(unsigned short, __float2bfloat16(f));
}

// ---------------- prep: X fp32 -> bf16 ----------------
__global__ __launch_bounds__(256) void convert_x_kernel(const float* __restrict__ X,
                                                        unsigned short* __restrict__ Xb){
  int i = blockIdx.x*256 + threadIdx.x;             // BS_*D_/4 threads
  float4v v = reinterpret_cast<const float4v*>(X)[i];
  us4 r;
  r[0]=f2bits(v[0]); r[1]=f2bits(v[1]); r[2]=f2bits(v[2]); r[3]=f2bits(v[3]);
  reinterpret_cast<us4*>(Xb)[i] = r;
}

// ---------------- prep: weight transpose+convert ----------------
__global__ __launch_bounds__(256) void prep_w_kernel(const float* __restrict__ Wq,
                                                     const float* __restrict__ Wk,
                                                     const float* __restrict__ Wv,
                                                     const float* __restrict__ Wo,
                                                     bf16* __restrict__ Wqt,
                                                     bf16* __restrict__ Wkt,
                                                     bf16* __restrict__ Wvt,
                                                     bf16* __restrict__ Wot){
  int t = blockIdx.x*256 + threadIdx.x;             // 4*32768 threads
  int s = t >> 15;
  int idx = t & 32767;
  if (s < 3){
    const float* src = (s==0)?Wq:((s==1)?Wk:Wv);
    bf16* dst = (s==0)?Wqt:((s==1)?Wkt:Wvt);
    int u = idx >> 8;          // /D_ = 256
    int d = idx & 255;
    dst[(size_t)u*D_ + d] = __float2bfloat16(src[(size_t)d*U_ + u]);
  } else {
    int dd = idx >> 7;         // /U_ = 128
    int u  = idx & 127;
    Wot[(size_t)dd*U_ + u] = __float2bfloat16(Wo[(size_t)u*D_ + dd]);
  }
}

// ---------------- QKV projection GEMM ----------------
__global__ __launch_bounds__(256) void qkv_kernel(const bf16* __restrict__ Xb,
                                                  const bf16* __restrict__ Wqt,
                                                  const bf16* __restrict__ Wkt,
                                                  const bf16* __restrict__ Wvt,
                                                  bf16* __restrict__ Q,
                                                  bf16* __restrict__ K,
                                                  bf16* __restrict__ Vt){
  const int which = blockIdx.y;
  const bf16* Wt = (which==0) ? Wqt : ((which==1) ? Wkt : Wvt);
  const int w    = threadIdx.x >> 6;
  const int lane = threadIdx.x & 63;
  const int lq   = lane & 15;
  const int g    = lane >> 4;
  const int m0   = blockIdx.x*64 + w*16;

  f4v acc[8];
  #pragma unroll
  for (int i=0;i<8;i++) acc[i] = (f4v){0.f,0.f,0.f,0.f};

  const bf16* xp = Xb + (size_t)(m0+lq)*D_ + g*8;
  #pragma unroll
  for (int k0=0;k0<D_;k0+=32){
    bf8v a = *reinterpret_cast<const bf8v*>(xp + k0);
    #pragma unroll
    for (int nc=0;nc<8;nc++){
      bf8v b = *reinterpret_cast<const bf8v*>(Wt + (size_t)(nc*16+lq)*D_ + k0 + g*8);
      acc[nc] = MFMA16(a, b, acc[nc]);
    }
  }

  if (which==0){
    const float qscale = 0.08838834764831845f;      // 1/sqrt(U)
    #pragma unroll
    for (int nc=0;nc<8;nc++){
      #pragma unroll
      for (int r=0;r<4;r++){
        Q[(size_t)(m0+g*4+r)*U_ + nc*16+lq] = __float2bfloat16(acc[nc][r]*qscale);
      }
    }
  } else if (which==1){
    #pragma unroll
    for (int nc=0;nc<8;nc++){
      #pragma unroll
      for (int r=0;r<4;r++){
        K[(size_t)(m0+g*4+r)*U_ + nc*16+lq] = __float2bfloat16(acc[nc][r]);
      }
    }
  } else {
    #pragma unroll
    for (int nc=0;nc<8;nc++){
      #pragma unroll
      for (int r=0;r<4;r++){
        int m = m0 + g*4 + r;
        int b = m >> 11;               // /S_
        int s = m & (S_-1);
        Vt[((size_t)b*U_ + nc*16+lq)*S_ + s] = __float2bfloat16(acc[nc][r]);
      }
    }
  }
}

// ---------------- flash attention: 32x32 MFMA, in-register softmax ----------------
// 512 blocks x 512 threads (8 waves). batch = blockIdx.x & 7 (XCD-aligned),
// q-tile (32 rows) = blockIdx.x >> 3. Wave w owns KV rows [w*256, (w+1)*256).
// QK^T swapped: S^T = mfma32(K_frag, Q_frag): C col = q = lane&31, rows = k.
// PV swapped:   O^T = mfma32(Vt_frag, P_frag): C col = q = lane&31, rows = u.
// Softmax stats and rescale are per-lane scalars; P re-layout in-register.
// Cross-wave combine via LDS in two u-passes (halves LDS -> 2 blocks/CU).
__global__ __launch_bounds__(512, 4) void flash_kernel(const bf16* __restrict__ Q,
                                                       const bf16* __restrict__ K,
                                                       const bf16* __restrict__ Vt,
                                                       bf16* __restrict__ O){
  __shared__ float Olds[8][64][33];    // per-wave O^T partial [u-half][q], pad 33
  __shared__ float mlds[8][32];
  __shared__ float llds[8][32];

  const int n    = blockIdx.x;
  const int b    = n & 7;
  const int qt   = n >> 3;
  const int w    = threadIdx.x >> 6;
  const int lane = threadIdx.x & 63;
  const int l5   = lane & 31;
  const int hi   = lane >> 5;
  const int q0   = qt * 32;

  // Q B-frags (pre-scaled by 1/sqrt(U)): lane holds Q[q0+l5][uc*16 + hi*8 + j]
  const bf16* Qp = Q + (size_t)(b*S_ + q0 + l5)*U_ + hi*8;
  bf8v qf[8];
  #pragma unroll
  for (int uc=0; uc<8; uc++) qf[uc] = *reinterpret_cast<const bf8v*>(Qp + uc*16);

  f16v o[4];
  #pragma unroll
  for (int uc=0; uc<4; uc++)
    #pragma unroll
    for (int r=0; r<16; r++) o[uc][r] = 0.f;

  float mrow = -1e30f, lrow = 0.f;

  const bf16* Kb = K  + (size_t)(b*S_ + l5)*U_ + hi*8;
  const bf16* Vb = Vt + ((size_t)b*U_ + l5)*S_ + hi*8;

  const int kbeg = w*(S_/8), kend = kbeg + S_/8;
  for (int k0=kbeg; k0<kend; k0+=32){
    // ---- QK^T ----
    f16v st0, st1;
    #pragma unroll
    for (int r=0;r<16;r++){ st0[r]=0.f; st1[r]=0.f; }
    const bf16* kp = Kb + (size_t)k0*U_;
    #pragma unroll
    for (int uc=0; uc<4; uc++){
      bf8v ka = *reinterpret_cast<const bf8v*>(kp + uc*32);
      bf8v kc = *reinterpret_cast<const bf8v*>(kp + uc*32 + 16);
      st0 = MFMA32(ka, qf[2*uc],   st0);
      st1 = MFMA32(kc, qf[2*uc+1], st1);
    }
    float p[16];
    #pragma unroll
    for (int r=0;r<16;r++) p[r] = st0[r] + st1[r];

    // ---- softmax stats (lane-local: col q = l5, rows k) ---- tree max
    float a0 = fmaxf(p[0],p[1]),  a1 = fmaxf(p[2],p[3]);
    float a2 = fmaxf(p[4],p[5]),  a3 = fmaxf(p[6],p[7]);
    float a4 = fmaxf(p[8],p[9]),  a5 = fmaxf(p[10],p[11]);
    float a6 = fmaxf(p[12],p[13]),a7 = fmaxf(p[14],p[15]);
    float b0 = fmaxf(a0,a1), b1 = fmaxf(a2,a3), b2 = fmaxf(a4,a5), b3 = fmaxf(a6,a7);
    float tm = fmaxf(fmaxf(b0,b1), fmaxf(b2,b3));
    tm = fmaxf(tm, __shfl_xor(tm, 32));

    if (!__all(tm <= mrow + 8.0f)){          // T13 defer-max
      float mn    = fmaxf(mrow, tm);
      float alpha = __expf(mrow - mn);
      lrow *= alpha;
      #pragma unroll
      for (int uc=0;uc<4;uc++)
        #pragma unroll
        for (int r=0;r<16;r++) o[uc][r] *= alpha;
      mrow = mn;
    }

    #pragma unroll
    for (int r=0;r<16;r++) p[r] = __expf(p[r]-mrow);
    float s0s = (p[0]+p[1]) + (p[2]+p[3]);
    float s1s = (p[4]+p[5]) + (p[6]+p[7]);
    float s2s = (p[8]+p[9]) + (p[10]+p[11]);
    float s3s = (p[12]+p[13]) + (p[14]+p[15]);
    float ts  = (s0s+s1s) + (s2s+s3s);
    ts += __shfl_xor(ts, 32);
    lrow += ts;

    // ---- P -> bf16 A/B-frags in-register ----
    // lane's p[r] = P[q=l5][k=(r&3)+8*(r>>2)+4*hi]
    unsigned c0 = (unsigned)f2bits(p[0])  | ((unsigned)f2bits(p[1])<<16);
    unsigned c1 = (unsigned)f2bits(p[2])  | ((unsigned)f2bits(p[3])<<16);
    unsigned c2 = (unsigned)f2bits(p[4])  | ((unsigned)f2bits(p[5])<<16);
    unsigned c3 = (unsigned)f2bits(p[6])  | ((unsigned)f2bits(p[7])<<16);
    unsigned c4 = (unsigned)f2bits(p[8])  | ((unsigned)f2bits(p[9])<<16);
    unsigned c5 = (unsigned)f2bits(p[10]) | ((unsigned)f2bits(p[11])<<16);
    unsigned c6 = (unsigned)f2bits(p[12]) | ((unsigned)f2bits(p[13])<<16);
    unsigned c7 = (unsigned)f2bits(p[14]) | ((unsigned)f2bits(p[15])<<16);
    unsigned sh0 = (unsigned)__shfl_xor((int)c0,32);
    unsigned sh1 = (unsigned)__shfl_xor((int)c1,32);
    unsigned sh2 = (unsigned)__shfl_xor((int)c2,32);
    unsigned sh3 = (unsigned)__shfl_xor((int)c3,32);
    unsigned sh4 = (unsigned)__shfl_xor((int)c4,32);
    unsigned sh5 = (unsigned)__shfl_xor((int)c5,32);
    unsigned sh6 = (unsigned)__shfl_xor((int)c6,32);
    unsigned sh7 = (unsigned)__shfl_xor((int)c7,32);
    u4v w0v, w1v;
    w0v[0] = hi ? sh2 : c0;  w0v[1] = hi ? sh3 : c1;
    w0v[2] = hi ? c2 : sh0;  w0v[3] = hi ? c3 : sh1;
    w1v[0] = hi ? sh6 : c4;  w1v[1] = hi ? sh7 : c5;
    w1v[2] = hi ? c6 : sh4;  w1v[3] = hi ? c7 : sh5;
    bf8v pa0 = __builtin_bit_cast(bf8v, w0v);   // P[q=l5][k = hi*8+j]      (k 0..15)
    bf8v pa1 = __builtin_bit_cast(bf8v, w1v);   // P[q=l5][k = 16+hi*8+j]   (k 16..31)

    // ---- PV: O^T += V^T-frag x P-frag ----
    const bf16* vp = Vb + k0;
    #pragma unroll
    for (int uc=0; uc<4; uc++){
      bf8v v0 = *reinterpret_cast<const bf8v*>(vp + (size_t)(uc*32)*S_);
      bf8v v1 = *reinterpret_cast<const bf8v*>(vp + (size_t)(uc*32)*S_ + 16);
      o[uc] = MFMA32(v0, pa0, o[uc]);
      o[uc] = MFMA32(v1, pa1, o[uc]);
    }
  }

  // ---- per-wave stats + partials (two u-passes over half-size LDS) ----
  if (hi==0){ mlds[w][l5] = mrow; llds[w][l5] = lrow; }

  // pass A: u in [0,64)  (o[0], o[1])
  #pragma unroll
  for (int uc=0; uc<2; uc++){
    #pragma unroll
    for (int r=0; r<16; r++){
      int u = uc*32 + (r&3) + 8*(r>>2) + 4*hi;
      Olds[w][u][l5] = o[uc][r];
    }
  }
  __syncthreads();

  // combine mapping: qrow = tid>>4 (0..31), u chunk = (tid&15)*4
  const int qrow = threadIdx.x >> 4;
  const int u4   = (threadIdx.x & 15) * 4;
  float mv[8], ev[8];
  #pragma unroll
  for (int i=0;i<8;i++) mv[i] = mlds[i][qrow];
  float M = fmaxf(fmaxf(fmaxf(mv[0],mv[1]),fmaxf(mv[2],mv[3])),
                  fmaxf(fmaxf(mv[4],mv[5]),fmaxf(mv[6],mv[7])));
  float L = 0.f;
  #pragma unroll
  for (int i=0;i<8;i++){ ev[i] = __expf(mv[i]-M); L += llds[i][qrow]*ev[i]; }
  float inv = 1.0f / L;

  bf16* Op = O + (size_t)(b*S_ + q0 + qrow)*U_;
  us4 outv;
  #pragma unroll
  for (int j=0;j<4;j++){
    float val = 0.f;
    #pragma unroll
    for (int i=0;i<8;i++) val += ev[i]*Olds[i][u4+j][qrow];
    outv[j] = f2bits(val*inv);
  }
  *reinterpret_cast<us4*>(Op + u4) = outv;
  __syncthreads();

  // pass B: u in [64,128) (o[2], o[3])
  #pragma unroll
  for (int uc=2; uc<4; uc++){
    #pragma unroll
    for (int r=0; r<16; r++){
      int u = (uc-2)*32 + (r&3) + 8*(r>>2) + 4*hi;
      Olds[w][u][l5] = o[uc][r];
    }
  }
  __syncthreads();

  #pragma unroll
  for (int j=0;j<4;j++){
    float val = 0.f;
    #pragma unroll
    for (int i=0;i<8;i++) val += ev[i]*Olds[i][u4+j][qrow];
    outv[j] = f2bits(val*inv);
  }
  *reinterpret_cast<us4*>(Op + 64 + u4) = outv;
}

// ---------------- output projection + residual ----------------
__global__ __launch_bounds__(256) void oproj_kernel(const bf16* __restrict__ O,
                                                    const bf16* __restrict__ Wot,
                                                    const float* __restrict__ X,
                                                    const float* __restrict__ bo,
                                                    float* __restrict__ Y){
  const int w    = threadIdx.x >> 6;
  const int lane = threadIdx.x & 63;
  const int lq   = lane & 15;
  const int g    = lane >> 4;
  const int m0   = blockIdx.x*64 + w*16;
  const int n0   = blockIdx.y*128;

  f4v acc[8];
  #pragma unroll
  for (int i=0;i<8;i++) acc[i] = (f4v){0.f,0.f,0.f,0.f};

  const bf16* op = O + (size_t)(m0+lq)*U_ + g*8;
  #pragma unroll
  for (int k0=0;k0<U_;k0+=32){
    bf8v a = *reinterpret_cast<const bf8v*>(op + k0);
    #pragma unroll
    for (int nc=0;nc<8;nc++){
      bf8v bb = *reinterpret_cast<const bf8v*>(Wot + (size_t)(n0+nc*16+lq)*U_ + k0 + g*8);
      acc[nc] = MFMA16(a, bb, acc[nc]);
    }
  }

  #pragma unroll
  for (int nc=0;nc<8;nc++){
    int col = n0 + nc*16 + lq;
    float bias = bo[col];
    #pragma unroll
    for (int r=0;r<4;r++){
      int row = m0 + g*4 + r;
      Y[(size_t)row*D_ + col] = acc[nc][r] + bias + X[(size_t)row*D_ + col];
    }
  }
}

extern "C" void kernel_launch(void* const* d_in, const int* in_sizes, int n_in,
                              void* d_out, int out_size, void* d_ws, size_t ws_size,
                              hipStream_t stream) {
  (void)in_sizes; (void)n_in; (void)out_size; (void)ws_size;
  const float* X  = (const float*)d_in[0];
  const float* Wq = (const float*)d_in[1];
  const float* Wk = (const float*)d_in[2];
  const float* Wv = (const float*)d_in[3];
  const float* Wo = (const float*)d_in[4];
  const float* bo = (const float*)d_in[5];
  float* Y = (float*)d_out;

  char* ws = (char*)d_ws;
  bf16* Xb  = (bf16*)(ws + 0);          // BS*D*2    = 8388608
  bf16* Qb  = (bf16*)(ws + 8388608);    // BS*U*2    = 4194304
  bf16* Kb  = (bf16*)(ws + 12582912);   // BS*U*2
  bf16* Vt  = (bf16*)(ws + 16777216);   // BS*U*2 (transposed per batch)
  bf16* Ob  = (bf16*)(ws + 20971520);   // BS*U*2
  bf16* Wqt = (bf16*)(ws + 25165824);   // U*D*2 = 65536
  bf16* Wkt = (bf16*)(ws + 25231360);
  bf16* Wvt = (bf16*)(ws + 25296896);
  bf16* Wot = (bf16*)(ws + 25362432);

  convert_x_kernel<<<dim3(BS_*D_/4/256), dim3(256), 0, stream>>>(X, (unsigned short*)Xb);
  prep_w_kernel<<<dim3(512), dim3(256), 0, stream>>>(Wq, Wk, Wv, Wo, Wqt, Wkt, Wvt, Wot);
  qkv_kernel<<<dim3(BS_/64, 3), dim3(256), 0, stream>>>(Xb, Wqt, Wkt, Wvt, Qb, Kb, Vt);
  flash_kernel<<<dim3(512), dim3(512), 0, stream>>>(Qb, Kb, Vt, Ob);
  oproj_kernel<<<dim3(BS_/64, 2), dim3(256), 0, stream>>>(Ob, Wot, X, bo, Y);
}

// Round 5
// 123.731 us; speedup vs baseline: 1.1250x; 1.1250x over previous
//
#include <hip/hip_runtime.h>
#include <hip/hip_bf16.h>

#define B_ 8
#define S_ 2048
#define D_ 256
#define U_ 128
#define BS_ (B_*S_)

using bf16 = __hip_bfloat16;
typedef __attribute__((ext_vector_type(8))) __bf16 bf8v;      // MFMA A/B frag (4 VGPR)
typedef __attribute__((ext_vector_type(4))) float f4v;        // 16x16 C/D frag
typedef __attribute__((ext_vector_type(16))) float f16v;      // 32x32 C/D frag
typedef __attribute__((ext_vector_type(4))) float float4v;
typedef __attribute__((ext_vector_type(4))) unsigned short us4;
typedef __attribute__((ext_vector_type(8))) unsigned short us8;
typedef __attribute__((ext_vector_type(4))) unsigned int u4v;

#define MFMA16(a,b,c) __builtin_amdgcn_mfma_f32_16x16x32_bf16((a),(b),(c),0,0,0)
#define MFMA32(a,b,c) __builtin_amdgcn_mfma_f32_32x32x16_bf16((a),(b),(c),0,0,0)

__device__ __forceinline__ unsigned short f2bits(float f){
  return __builtin_bit_cast(unsigned short, __float2bfloat16(f));
}
__device__ __forceinline__ float b2f(unsigned short u){
  return __builtin_bit_cast(float, ((unsigned)u) << 16);
}

// ---------------- prep: X fp32 -> bf16 ----------------
__global__ __launch_bounds__(256) void convert_x_kernel(const float* __restrict__ X,
                                                        unsigned short* __restrict__ Xb){
  int i = blockIdx.x*256 + threadIdx.x;             // BS_*D_/4 threads
  float4v v = reinterpret_cast<const float4v*>(X)[i];
  us4 r;
  r[0]=f2bits(v[0]); r[1]=f2bits(v[1]); r[2]=f2bits(v[2]); r[3]=f2bits(v[3]);
  reinterpret_cast<us4*>(Xb)[i] = r;
}

// ---------------- prep: weight transpose+convert ----------------
__global__ __launch_bounds__(256) void prep_w_kernel(const float* __restrict__ Wq,
                                                     const float* __restrict__ Wk,
                                                     const float* __restrict__ Wv,
                                                     const float* __restrict__ Wo,
                                                     bf16* __restrict__ Wqt,
                                                     bf16* __restrict__ Wkt,
                                                     bf16* __restrict__ Wvt,
                                                     bf16* __restrict__ Wot){
  int t = blockIdx.x*256 + threadIdx.x;             // 4*32768 threads
  int s = t >> 15;
  int idx = t & 32767;
  if (s < 3){
    const float* src = (s==0)?Wq:((s==1)?Wk:Wv);
    bf16* dst = (s==0)?Wqt:((s==1)?Wkt:Wvt);
    int u = idx >> 8;          // /D_ = 256
    int d = idx & 255;
    dst[(size_t)u*D_ + d] = __float2bfloat16(src[(size_t)d*U_ + u]);
  } else {
    int dd = idx >> 7;         // /U_ = 128
    int u  = idx & 127;
    Wot[(size_t)dd*U_ + u] = __float2bfloat16(Wo[(size_t)u*D_ + dd]);
  }
}

// ---------------- QKV projection GEMM ----------------
__global__ __launch_bounds__(256) void qkv_kernel(const bf16* __restrict__ Xb,
                                                  const bf16* __restrict__ Wqt,
                                                  const bf16* __restrict__ Wkt,
                                                  const bf16* __restrict__ Wvt,
                                                  bf16* __restrict__ Q,
                                                  bf16* __restrict__ K,
                                                  bf16* __restrict__ Vt){
  const int which = blockIdx.y;
  const bf16* Wt = (which==0) ? Wqt : ((which==1) ? Wkt : Wvt);
  const int w    = threadIdx.x >> 6;
  const int lane = threadIdx.x & 63;
  const int lq   = lane & 15;
  const int g    = lane >> 4;
  const int m0   = blockIdx.x*64 + w*16;

  f4v acc[8];
  #pragma unroll
  for (int i=0;i<8;i++) acc[i] = (f4v){0.f,0.f,0.f,0.f};

  const bf16* xp = Xb + (size_t)(m0+lq)*D_ + g*8;
  #pragma unroll
  for (int k0=0;k0<D_;k0+=32){
    bf8v a = *reinterpret_cast<const bf8v*>(xp + k0);
    #pragma unroll
    for (int nc=0;nc<8;nc++){
      bf8v b = *reinterpret_cast<const bf8v*>(Wt + (size_t)(nc*16+lq)*D_ + k0 + g*8);
      acc[nc] = MFMA16(a, b, acc[nc]);
    }
  }

  if (which==0){
    const float qscale = 0.08838834764831845f;      // 1/sqrt(U)
    #pragma unroll
    for (int nc=0;nc<8;nc++){
      #pragma unroll
      for (int r=0;r<4;r++){
        Q[(size_t)(m0+g*4+r)*U_ + nc*16+lq] = __float2bfloat16(acc[nc][r]*qscale);
      }
    }
  } else if (which==1){
    #pragma unroll
    for (int nc=0;nc<8;nc++){
      #pragma unroll
      for (int r=0;r<4;r++){
        K[(size_t)(m0+g*4+r)*U_ + nc*16+lq] = __float2bfloat16(acc[nc][r]);
      }
    }
  } else {
    #pragma unroll
    for (int nc=0;nc<8;nc++){
      #pragma unroll
      for (int r=0;r<4;r++){
        int m = m0 + g*4 + r;
        int b = m >> 11;               // /S_
        int s = m & (S_-1);
        Vt[((size_t)b*U_ + nc*16+lq)*S_ + s] = __float2bfloat16(acc[nc][r]);
      }
    }
  }
}

// ---------------- flash attention: 32x32 MFMA, in-register softmax ----------------
// Global split-KV x2: 1024 blocks x 256 threads (4 waves).
// blockIdx.x = qt*16 + half*8 + b  (batch on low bits -> XCD-aligned).
// Wave w owns KV rows [half*1024 + w*256, +256). 32 q-rows per block.
// QK^T swapped: S^T = mfma32(K_frag, Q_frag): C col = q = lane&31, rows = k.
// PV swapped:   O^T = mfma32(Vt_frag, P_frag): C col = q = lane&31, rows = u.
// Block writes normalized partial O (bf16) + merged (m,l) stats (fp32).
__global__ __launch_bounds__(256) void flash_kernel(const bf16* __restrict__ Q,
                                                    const bf16* __restrict__ K,
                                                    const bf16* __restrict__ Vt,
                                                    bf16* __restrict__ Opart,
                                                    float* __restrict__ Mst,
                                                    float* __restrict__ Lst){
  __shared__ float Olds[4][64][33];    // per-wave O^T partial [u-half][q], pad 33
  __shared__ float mlds[4][32];
  __shared__ float llds[4][32];

  const int n    = blockIdx.x;
  const int b    = n & 7;
  const int half = (n >> 3) & 1;
  const int qt   = n >> 4;
  const int w    = threadIdx.x >> 6;
  const int lane = threadIdx.x & 63;
  const int l5   = lane & 31;
  const int hi   = lane >> 5;
  const int q0   = qt * 32;

  // Q B-frags (pre-scaled by 1/sqrt(U)): lane holds Q[q0+l5][uc*16 + hi*8 + j]
  const bf16* Qp = Q + (size_t)(b*S_ + q0 + l5)*U_ + hi*8;
  bf8v qf[8];
  #pragma unroll
  for (int uc=0; uc<8; uc++) qf[uc] = *reinterpret_cast<const bf8v*>(Qp + uc*16);

  f16v o[4];
  #pragma unroll
  for (int uc=0; uc<4; uc++)
    #pragma unroll
    for (int r=0; r<16; r++) o[uc][r] = 0.f;

  float mrow = -1e30f, lrow = 0.f;

  const bf16* Kb = K  + (size_t)(b*S_ + l5)*U_ + hi*8;
  const bf16* Vb = Vt + ((size_t)b*U_ + l5)*S_ + hi*8;

  const int kbeg = half*(S_/2) + w*(S_/8), kend = kbeg + S_/8;
  for (int k0=kbeg; k0<kend; k0+=32){
    // ---- QK^T ----
    f16v st0, st1;
    #pragma unroll
    for (int r=0;r<16;r++){ st0[r]=0.f; st1[r]=0.f; }
    const bf16* kp = Kb + (size_t)k0*U_;
    #pragma unroll
    for (int uc=0; uc<4; uc++){
      bf8v ka = *reinterpret_cast<const bf8v*>(kp + uc*32);
      bf8v kc = *reinterpret_cast<const bf8v*>(kp + uc*32 + 16);
      st0 = MFMA32(ka, qf[2*uc],   st0);
      st1 = MFMA32(kc, qf[2*uc+1], st1);
    }
    float p[16];
    #pragma unroll
    for (int r=0;r<16;r++) p[r] = st0[r] + st1[r];

    // ---- softmax stats (lane-local: col q = l5, rows k) ---- tree max
    float a0 = fmaxf(p[0],p[1]),  a1 = fmaxf(p[2],p[3]);
    float a2 = fmaxf(p[4],p[5]),  a3 = fmaxf(p[6],p[7]);
    float a4 = fmaxf(p[8],p[9]),  a5 = fmaxf(p[10],p[11]);
    float a6 = fmaxf(p[12],p[13]),a7 = fmaxf(p[14],p[15]);
    float b0 = fmaxf(a0,a1), b1 = fmaxf(a2,a3), b2 = fmaxf(a4,a5), b3 = fmaxf(a6,a7);
    float tm = fmaxf(fmaxf(b0,b1), fmaxf(b2,b3));
    tm = fmaxf(tm, __shfl_xor(tm, 32));

    if (!__all(tm <= mrow + 8.0f)){          // T13 defer-max
      float mn    = fmaxf(mrow, tm);
      float alpha = __expf(mrow - mn);
      lrow *= alpha;
      #pragma unroll
      for (int uc=0;uc<4;uc++)
        #pragma unroll
        for (int r=0;r<16;r++) o[uc][r] *= alpha;
      mrow = mn;
    }

    #pragma unroll
    for (int r=0;r<16;r++) p[r] = __expf(p[r]-mrow);
    float s0s = (p[0]+p[1]) + (p[2]+p[3]);
    float s1s = (p[4]+p[5]) + (p[6]+p[7]);
    float s2s = (p[8]+p[9]) + (p[10]+p[11]);
    float s3s = (p[12]+p[13]) + (p[14]+p[15]);
    float ts  = (s0s+s1s) + (s2s+s3s);
    ts += __shfl_xor(ts, 32);
    lrow += ts;

    // ---- P -> bf16 A/B-frags in-register ----
    // lane's p[r] = P[q=l5][k=(r&3)+8*(r>>2)+4*hi]
    unsigned c0 = (unsigned)f2bits(p[0])  | ((unsigned)f2bits(p[1])<<16);
    unsigned c1 = (unsigned)f2bits(p[2])  | ((unsigned)f2bits(p[3])<<16);
    unsigned c2 = (unsigned)f2bits(p[4])  | ((unsigned)f2bits(p[5])<<16);
    unsigned c3 = (unsigned)f2bits(p[6])  | ((unsigned)f2bits(p[7])<<16);
    unsigned c4 = (unsigned)f2bits(p[8])  | ((unsigned)f2bits(p[9])<<16);
    unsigned c5 = (unsigned)f2bits(p[10]) | ((unsigned)f2bits(p[11])<<16);
    unsigned c6 = (unsigned)f2bits(p[12]) | ((unsigned)f2bits(p[13])<<16);
    unsigned c7 = (unsigned)f2bits(p[14]) | ((unsigned)f2bits(p[15])<<16);
    unsigned sh0 = (unsigned)__shfl_xor((int)c0,32);
    unsigned sh1 = (unsigned)__shfl_xor((int)c1,32);
    unsigned sh2 = (unsigned)__shfl_xor((int)c2,32);
    unsigned sh3 = (unsigned)__shfl_xor((int)c3,32);
    unsigned sh4 = (unsigned)__shfl_xor((int)c4,32);
    unsigned sh5 = (unsigned)__shfl_xor((int)c5,32);
    unsigned sh6 = (unsigned)__shfl_xor((int)c6,32);
    unsigned sh7 = (unsigned)__shfl_xor((int)c7,32);
    u4v w0v, w1v;
    w0v[0] = hi ? sh2 : c0;  w0v[1] = hi ? sh3 : c1;
    w0v[2] = hi ? c2 : sh0;  w0v[3] = hi ? c3 : sh1;
    w1v[0] = hi ? sh6 : c4;  w1v[1] = hi ? sh7 : c5;
    w1v[2] = hi ? c6 : sh4;  w1v[3] = hi ? c7 : sh5;
    bf8v pa0 = __builtin_bit_cast(bf8v, w0v);   // P[q=l5][k = hi*8+j]      (k 0..15)
    bf8v pa1 = __builtin_bit_cast(bf8v, w1v);   // P[q=l5][k = 16+hi*8+j]   (k 16..31)

    // ---- PV: O^T += V^T-frag x P-frag ----
    const bf16* vp = Vb + k0;
    #pragma unroll
    for (int uc=0; uc<4; uc++){
      bf8v v0 = *reinterpret_cast<const bf8v*>(vp + (size_t)(uc*32)*S_);
      bf8v v1 = *reinterpret_cast<const bf8v*>(vp + (size_t)(uc*32)*S_ + 16);
      o[uc] = MFMA32(v0, pa0, o[uc]);
      o[uc] = MFMA32(v1, pa1, o[uc]);
    }
  }

  // ---- per-wave stats, then two u-passes over half-size LDS ----
  if (hi==0){ mlds[w][l5] = mrow; llds[w][l5] = lrow; }

  // pass A: u in [0,64)  (o[0], o[1])
  #pragma unroll
  for (int uc=0; uc<2; uc++){
    #pragma unroll
    for (int r=0; r<16; r++){
      int u = uc*32 + (r&3) + 8*(r>>2) + 4*hi;
      Olds[w][u][l5] = o[uc][r];
    }
  }
  __syncthreads();

  // combine mapping: qrow = tid>>3 (0..31), u chunk = (tid&7)*8
  const int qrow = threadIdx.x >> 3;
  const int uc8  = (threadIdx.x & 7) * 8;
  float mv[4], ev[4];
  #pragma unroll
  for (int i=0;i<4;i++) mv[i] = mlds[i][qrow];
  float M = fmaxf(fmaxf(mv[0],mv[1]), fmaxf(mv[2],mv[3]));
  float L = 0.f;
  #pragma unroll
  for (int i=0;i<4;i++){ ev[i] = __expf(mv[i]-M); L += llds[i][qrow]*ev[i]; }
  float inv = 1.0f / L;

  const size_t rowg = (size_t)(b*S_ + q0 + qrow);
  if ((threadIdx.x & 7) == 0){
    Mst[(size_t)half*BS_ + rowg] = M;
    Lst[(size_t)half*BS_ + rowg] = L;
  }

  bf16* Op = Opart + (size_t)half*BS_*U_ + rowg*U_;
  us8 outv;
  #pragma unroll
  for (int j=0;j<8;j++){
    float val = 0.f;
    #pragma unroll
    for (int i=0;i<4;i++) val += ev[i]*Olds[i][uc8+j][qrow];
    outv[j] = f2bits(val*inv);
  }
  *reinterpret_cast<us8*>(Op + uc8) = outv;
  __syncthreads();

  // pass B: u in [64,128) (o[2], o[3])
  #pragma unroll
  for (int uc=2; uc<4; uc++){
    #pragma unroll
    for (int r=0; r<16; r++){
      int u = (uc-2)*32 + (r&3) + 8*(r>>2) + 4*hi;
      Olds[w][u][l5] = o[uc][r];
    }
  }
  __syncthreads();

  #pragma unroll
  for (int j=0;j<8;j++){
    float val = 0.f;
    #pragma unroll
    for (int i=0;i<4;i++) val += ev[i]*Olds[i][uc8+j][qrow];
    outv[j] = f2bits(val*inv);
  }
  *reinterpret_cast<us8*>(Op + 64 + uc8) = outv;
}

// ---------------- combine the two KV halves ----------------
// O[row][u] = (w0*O0 + w1*O1), w_i = l_i*exp(m_i-M) normalized.
__global__ __launch_bounds__(256) void combine_kernel(const bf16* __restrict__ Opart,
                                                      const float* __restrict__ Mst,
                                                      const float* __restrict__ Lst,
                                                      bf16* __restrict__ O){
  int idx = blockIdx.x*256 + threadIdx.x;   // BS*U/8 threads
  int row = idx >> 4;
  int uc8 = (idx & 15) * 8;
  float m0 = Mst[row], m1 = Mst[BS_+row];
  float l0 = Lst[row], l1 = Lst[BS_+row];
  float M  = fmaxf(m0,m1);
  float w0 = l0*__expf(m0-M), w1 = l1*__expf(m1-M);
  float inv = 1.0f/(w0+w1);
  w0 *= inv; w1 *= inv;
  const size_t off = (size_t)row*U_ + uc8;
  us8 p0 = *reinterpret_cast<const us8*>(reinterpret_cast<const unsigned short*>(Opart) + off);
  us8 p1 = *reinterpret_cast<const us8*>(reinterpret_cast<const unsigned short*>(Opart) + (size_t)BS_*U_ + off);
  us8 outv;
  #pragma unroll
  for (int j=0;j<8;j++) outv[j] = f2bits(w0*b2f(p0[j]) + w1*b2f(p1[j]));
  *reinterpret_cast<us8*>(reinterpret_cast<unsigned short*>(O) + off) = outv;
}

// ---------------- output projection + residual ----------------
__global__ __launch_bounds__(256) void oproj_kernel(const bf16* __restrict__ O,
                                                    const bf16* __restrict__ Wot,
                                                    const float* __restrict__ X,
                                                    const float* __restrict__ bo,
                                                    float* __restrict__ Y){
  const int w    = threadIdx.x >> 6;
  const int lane = threadIdx.x & 63;
  const int lq   = lane & 15;
  const int g    = lane >> 4;
  const int m0   = blockIdx.x*64 + w*16;
  const int n0   = blockIdx.y*128;

  f4v acc[8];
  #pragma unroll
  for (int i=0;i<8;i++) acc[i] = (f4v){0.f,0.f,0.f,0.f};

  const bf16* op = O + (size_t)(m0+lq)*U_ + g*8;
  #pragma unroll
  for (int k0=0;k0<U_;k0+=32){
    bf8v a = *reinterpret_cast<const bf8v*>(op + k0);
    #pragma unroll
    for (int nc=0;nc<8;nc++){
      bf8v bb = *reinterpret_cast<const bf8v*>(Wot + (size_t)(n0+nc*16+lq)*U_ + k0 + g*8);
      acc[nc] = MFMA16(a, bb, acc[nc]);
    }
  }

  #pragma unroll
  for (int nc=0;nc<8;nc++){
    int col = n0 + nc*16 + lq;
    float bias = bo[col];
    #pragma unroll
    for (int r=0;r<4;r++){
      int row = m0 + g*4 + r;
      Y[(size_t)row*D_ + col] = acc[nc][r] + bias + X[(size_t)row*D_ + col];
    }
  }
}

extern "C" void kernel_launch(void* const* d_in, const int* in_sizes, int n_in,
                              void* d_out, int out_size, void* d_ws, size_t ws_size,
                              hipStream_t stream) {
  (void)in_sizes; (void)n_in; (void)out_size; (void)ws_size;
  const float* X  = (const float*)d_in[0];
  const float* Wq = (const float*)d_in[1];
  const float* Wk = (const float*)d_in[2];
  const float* Wv = (const float*)d_in[3];
  const float* Wo = (const float*)d_in[4];
  const float* bo = (const float*)d_in[5];
  float* Y = (float*)d_out;

  char* ws = (char*)d_ws;
  bf16* Xb  = (bf16*)(ws + 0);          // BS*D*2    = 8388608 (dead after qkv)
  bf16* Opart = (bf16*)(ws + 0);        // 2 * BS*U*2 = 8388608 (aliases Xb)
  bf16* Qb  = (bf16*)(ws + 8388608);    // BS*U*2    = 4194304
  bf16* Kb  = (bf16*)(ws + 12582912);   // BS*U*2
  bf16* Vt  = (bf16*)(ws + 16777216);   // BS*U*2 (transposed per batch)
  bf16* Ob  = (bf16*)(ws + 20971520);   // BS*U*2
  bf16* Wqt = (bf16*)(ws + 25165824);   // U*D*2 = 65536
  bf16* Wkt = (bf16*)(ws + 25231360);
  bf16* Wvt = (bf16*)(ws + 25296896);
  bf16* Wot = (bf16*)(ws + 25362432);
  float* Mst = (float*)(ws + 25427968); // 2*BS*4 = 131072
  float* Lst = (float*)(ws + 25559040); // 2*BS*4 = 131072

  convert_x_kernel<<<dim3(BS_*D_/4/256), dim3(256), 0, stream>>>(X, (unsigned short*)Xb);
  prep_w_kernel<<<dim3(512), dim3(256), 0, stream>>>(Wq, Wk, Wv, Wo, Wqt, Wkt, Wvt, Wot);
  qkv_kernel<<<dim3(BS_/64, 3), dim3(256), 0, stream>>>(Xb, Wqt, Wkt, Wvt, Qb, Kb, Vt);
  flash_kernel<<<dim3(1024), dim3(256), 0, stream>>>(Qb, Kb, Vt, Opart, Mst, Lst);
  combine_kernel<<<dim3(BS_*U_/8/256), dim3(256), 0, stream>>>(Opart, Mst, Lst, Ob);
  oproj_kernel<<<dim3(BS_/64, 2), dim3(256), 0, stream>>>(Ob, Wot, X, bo, Y);
}

// Round 6
// 109.296 us; speedup vs baseline: 1.2736x; 1.1321x over previous
//
#include <hip/hip_runtime.h>
#include <hip/hip_bf16.h>

#define B_ 8
#define S_ 2048
#define D_ 256
#define U_ 128
#define BS_ (B_*S_)

using bf16 = __hip_bfloat16;
typedef __attribute__((ext_vector_type(8))) __bf16 bf8v;      // MFMA A/B frag (4 VGPR)
typedef __attribute__((ext_vector_type(4))) float f4v;        // 16x16 C/D frag
typedef __attribute__((ext_vector_type(16))) float f16v;      // 32x32 C/D frag
typedef __attribute__((ext_vector_type(4))) float float4v;
typedef __attribute__((ext_vector_type(4))) unsigned short us4;
typedef __attribute__((ext_vector_type(8))) unsigned short us8;
typedef __attribute__((ext_vector_type(4))) unsigned int u4v;

#define MFMA16(a,b,c) __builtin_amdgcn_mfma_f32_16x16x32_bf16((a),(b),(c),0,0,0)
#define MFMA32(a,b,c) __builtin_amdgcn_mfma_f32_32x32x16_bf16((a),(b),(c),0,0,0)

__device__ __forceinline__ unsigned short f2bits(float f){
  return __builtin_bit_cast(unsigned short, __float2bfloat16(f));
}
__device__ __forceinline__ float b2f(unsigned short u){
  return __builtin_bit_cast(float, ((unsigned)u) << 16);
}

// async global->LDS, 16B per lane; LDS dest = wave-uniform base + lane*16
__device__ __forceinline__ void gload16(const void* g, void* l){
  __builtin_amdgcn_global_load_lds(
    (const __attribute__((address_space(1))) char*)(unsigned long long)g,
    (__attribute__((address_space(3))) char*)(unsigned int)(unsigned long long)l,
    16, 0, 0);
}

// ---------------- prep: X fp32 -> bf16 ----------------
__global__ __launch_bounds__(256) void convert_x_kernel(const float* __restrict__ X,
                                                        unsigned short* __restrict__ Xb){
  int i = blockIdx.x*256 + threadIdx.x;             // BS_*D_/4 threads
  float4v v = reinterpret_cast<const float4v*>(X)[i];
  us4 r;
  r[0]=f2bits(v[0]); r[1]=f2bits(v[1]); r[2]=f2bits(v[2]); r[3]=f2bits(v[3]);
  reinterpret_cast<us4*>(Xb)[i] = r;
}

// ---------------- prep: weight transpose+convert ----------------
__global__ __launch_bounds__(256) void prep_w_kernel(const float* __restrict__ Wq,
                                                     const float* __restrict__ Wk,
                                                     const float* __restrict__ Wv,
                                                     const float* __restrict__ Wo,
                                                     bf16* __restrict__ Wqt,
                                                     bf16* __restrict__ Wkt,
                                                     bf16* __restrict__ Wvt,
                                                     bf16* __restrict__ Wot){
  int t = blockIdx.x*256 + threadIdx.x;             // 4*32768 threads
  int s = t >> 15;
  int idx = t & 32767;
  if (s < 3){
    const float* src = (s==0)?Wq:((s==1)?Wk:Wv);
    bf16* dst = (s==0)?Wqt:((s==1)?Wkt:Wvt);
    int u = idx >> 8;          // /D_ = 256
    int d = idx & 255;
    dst[(size_t)u*D_ + d] = __float2bfloat16(src[(size_t)d*U_ + u]);
  } else {
    int dd = idx >> 7;         // /U_ = 128
    int u  = idx & 127;
    Wot[(size_t)dd*U_ + u] = __float2bfloat16(Wo[(size_t)u*D_ + dd]);
  }
}

// ---------------- QKV projection GEMM ----------------
__global__ __launch_bounds__(256) void qkv_kernel(const bf16* __restrict__ Xb,
                                                  const bf16* __restrict__ Wqt,
                                                  const bf16* __restrict__ Wkt,
                                                  const bf16* __restrict__ Wvt,
                                                  bf16* __restrict__ Q,
                                                  bf16* __restrict__ K,
                                                  bf16* __restrict__ Vt){
  const int which = blockIdx.y;
  const bf16* Wt = (which==0) ? Wqt : ((which==1) ? Wkt : Wvt);
  const int w    = threadIdx.x >> 6;
  const int lane = threadIdx.x & 63;
  const int lq   = lane & 15;
  const int g    = lane >> 4;
  const int m0   = blockIdx.x*64 + w*16;

  f4v acc[8];
  #pragma unroll
  for (int i=0;i<8;i++) acc[i] = (f4v){0.f,0.f,0.f,0.f};

  const bf16* xp = Xb + (size_t)(m0+lq)*D_ + g*8;
  #pragma unroll
  for (int k0=0;k0<D_;k0+=32){
    bf8v a = *reinterpret_cast<const bf8v*>(xp + k0);
    #pragma unroll
    for (int nc=0;nc<8;nc++){
      bf8v b = *reinterpret_cast<const bf8v*>(Wt + (size_t)(nc*16+lq)*D_ + k0 + g*8);
      acc[nc] = MFMA16(a, b, acc[nc]);
    }
  }

  if (which==0){
    const float qscale = 0.08838834764831845f;      // 1/sqrt(U)
    #pragma unroll
    for (int nc=0;nc<8;nc++){
      #pragma unroll
      for (int r=0;r<4;r++){
        Q[(size_t)(m0+g*4+r)*U_ + nc*16+lq] = __float2bfloat16(acc[nc][r]*qscale);
      }
    }
  } else if (which==1){
    #pragma unroll
    for (int nc=0;nc<8;nc++){
      #pragma unroll
      for (int r=0;r<4;r++){
        K[(size_t)(m0+g*4+r)*U_ + nc*16+lq] = __float2bfloat16(acc[nc][r]);
      }
    }
  } else {
    #pragma unroll
    for (int nc=0;nc<8;nc++){
      #pragma unroll
      for (int r=0;r<4;r++){
        int m = m0 + g*4 + r;
        int b = m >> 11;               // /S_
        int s = m & (S_-1);
        Vt[((size_t)b*U_ + nc*16+lq)*S_ + s] = __float2bfloat16(acc[nc][r]);
      }
    }
  }
}

// ---------------- flash attention: K staged in LDS (2-phase dbuf), 32x32 MFMA ----------------
// grid = 16*nsplit*8 blocks x 256 thr (4 waves). blockIdx.x = (qt*nsplit+s)*8 + b.
// Each wave owns a DIFFERENT 32-q tile (q0 = qt*128 + w*32); all 4 waves share the K stream.
// K tile [32][128] bf16 staged via global_load_lds with pre-swizzled source
// (byte ^= (row&7)<<4), read back with the same XOR -> conflict-free ds_read_b128.
// V frags read from global (L1-shared across the 4 waves), prefetched into regs.
// Counted vmcnt(2) + raw s_barrier keeps next-tile staging in flight across compute.
__global__ __launch_bounds__(256) void flash_kernel(const bf16* __restrict__ Q,
                                                    const bf16* __restrict__ K,
                                                    const bf16* __restrict__ Vt,
                                                    bf16* __restrict__ Opart,
                                                    float* __restrict__ Mst,
                                                    float* __restrict__ Lst,
                                                    int nsplit){
  __shared__ bf16 Kls[2][32*128];      // 2 x 8KB

  const int n    = blockIdx.x;
  const int b    = n & 7;
  const int m    = n >> 3;
  const int s    = m % nsplit;
  const int qt   = m / nsplit;
  const int w    = threadIdx.x >> 6;
  const int lane = threadIdx.x & 63;
  const int l5   = lane & 31;
  const int hi   = lane >> 5;
  const int q0   = qt*128 + w*32;

  const int t0 = (s*64)/nsplit;
  const int t1 = ((s+1)*64)/nsplit;

  // Q B-frags (pre-scaled by 1/sqrt(U)): lane holds Q[q0+l5][uc*16 + hi*8 + j]
  const bf16* Qp = Q + (size_t)(b*S_ + q0 + l5)*U_ + hi*8;
  bf8v qf[8];
  #pragma unroll
  for (int uc=0; uc<8; uc++) qf[uc] = *reinterpret_cast<const bf8v*>(Qp + uc*16);

  f16v o[4];
  #pragma unroll
  for (int uc=0; uc<4; uc++)
    #pragma unroll
    for (int r=0; r<16; r++) o[uc][r] = 0.f;

  float mrow = -1e30f, lrow = 0.f;

  const bf16* Vb    = Vt + ((size_t)b*U_ + l5)*S_ + hi*8;
  const bf16* Kbase = K + (size_t)b*S_*U_;

  // stage K tile t into buffer buf: wave w covers rows [w*8, w*8+8)
  auto stage = [&](int buf, int t){
    const int r0 = w*8;
    #pragma unroll
    for (int c=0; c<2; c++){
      int row  = r0 + c*4 + (lane>>4);
      int soff = ((lane&15)<<4) ^ ((row&7)<<4);
      const char* src = (const char*)(Kbase + (size_t)(t*32 + row)*U_) + soff;
      gload16(src, (void*)&Kls[buf][(r0 + c*4)*128]);
    }
  };

  stage(0, t0);
  int cur = 0;
  for (int tt=t0; tt<t1; ++tt){
    int tn = (tt+1 < 64) ? (tt+1) : 63;
    stage(cur^1, tn);                                  // 2 vmem ops in flight for t+1
    asm volatile("s_waitcnt vmcnt(2)" ::: "memory");   // tile tt (staged last iter) complete
    __builtin_amdgcn_s_barrier();
    unsigned bufoff = (unsigned)cur * 8192u;           // launder: pin LDS reads after barrier
    asm volatile("" : "+v"(bufoff) : : "memory");
    const char* kb = (const char*)&Kls[0][0] + bufoff;

    // V prefetch for this tile (overlaps QK^T + softmax)
    const bf16* vp = Vb + tt*32;
    bf8v v0[4], v1[4];
    #pragma unroll
    for (int uc=0; uc<4; uc++){
      v0[uc] = *reinterpret_cast<const bf8v*>(vp + (size_t)(uc*32)*S_);
      v1[uc] = *reinterpret_cast<const bf8v*>(vp + (size_t)(uc*32)*S_ + 16);
    }

    // ---- QK^T from LDS (swizzled reads) ----
    f16v st0, st1;
    #pragma unroll
    for (int r=0;r<16;r++){ st0[r]=0.f; st1[r]=0.f; }
    #pragma unroll
    for (int uc=0; uc<4; uc++){
      bf8v ka = *reinterpret_cast<const bf8v*>(kb + l5*256 + ((uc*64      + hi*16) ^ ((l5&7)<<4)));
      bf8v kc = *reinterpret_cast<const bf8v*>(kb + l5*256 + ((uc*64 + 32 + hi*16) ^ ((l5&7)<<4)));
      st0 = MFMA32(ka, qf[2*uc],   st0);
      st1 = MFMA32(kc, qf[2*uc+1], st1);
    }
    float p[16];
    #pragma unroll
    for (int r=0;r<16;r++) p[r] = st0[r] + st1[r];

    // ---- softmax stats (lane-local: col q = l5, rows k) ----
    float a0 = fmaxf(p[0],p[1]),  a1 = fmaxf(p[2],p[3]);
    float a2 = fmaxf(p[4],p[5]),  a3 = fmaxf(p[6],p[7]);
    float a4 = fmaxf(p[8],p[9]),  a5 = fmaxf(p[10],p[11]);
    float a6 = fmaxf(p[12],p[13]),a7 = fmaxf(p[14],p[15]);
    float b0 = fmaxf(a0,a1), b1 = fmaxf(a2,a3), b2 = fmaxf(a4,a5), b3 = fmaxf(a6,a7);
    float tm = fmaxf(fmaxf(b0,b1), fmaxf(b2,b3));
    tm = fmaxf(tm, __shfl_xor(tm, 32));

    if (!__all(tm <= mrow + 8.0f)){          // T13 defer-max
      float mn    = fmaxf(mrow, tm);
      float alpha = __expf(mrow - mn);
      lrow *= alpha;
      #pragma unroll
      for (int uc=0;uc<4;uc++)
        #pragma unroll
        for (int r=0;r<16;r++) o[uc][r] *= alpha;
      mrow = mn;
    }

    #pragma unroll
    for (int r=0;r<16;r++) p[r] = __expf(p[r]-mrow);
    float s0s = (p[0]+p[1]) + (p[2]+p[3]);
    float s1s = (p[4]+p[5]) + (p[6]+p[7]);
    float s2s = (p[8]+p[9]) + (p[10]+p[11]);
    float s3s = (p[12]+p[13]) + (p[14]+p[15]);
    float ts  = (s0s+s1s) + (s2s+s3s);
    ts += __shfl_xor(ts, 32);
    lrow += ts;

    // ---- P -> bf16 A/B-frags in-register ----
    unsigned c0 = (unsigned)f2bits(p[0])  | ((unsigned)f2bits(p[1])<<16);
    unsigned c1 = (unsigned)f2bits(p[2])  | ((unsigned)f2bits(p[3])<<16);
    unsigned c2 = (unsigned)f2bits(p[4])  | ((unsigned)f2bits(p[5])<<16);
    unsigned c3 = (unsigned)f2bits(p[6])  | ((unsigned)f2bits(p[7])<<16);
    unsigned c4 = (unsigned)f2bits(p[8])  | ((unsigned)f2bits(p[9])<<16);
    unsigned c5 = (unsigned)f2bits(p[10]) | ((unsigned)f2bits(p[11])<<16);
    unsigned c6 = (unsigned)f2bits(p[12]) | ((unsigned)f2bits(p[13])<<16);
    unsigned c7 = (unsigned)f2bits(p[14]) | ((unsigned)f2bits(p[15])<<16);
    unsigned sh0 = (unsigned)__shfl_xor((int)c0,32);
    unsigned sh1 = (unsigned)__shfl_xor((int)c1,32);
    unsigned sh2 = (unsigned)__shfl_xor((int)c2,32);
    unsigned sh3 = (unsigned)__shfl_xor((int)c3,32);
    unsigned sh4 = (unsigned)__shfl_xor((int)c4,32);
    unsigned sh5 = (unsigned)__shfl_xor((int)c5,32);
    unsigned sh6 = (unsigned)__shfl_xor((int)c6,32);
    unsigned sh7 = (unsigned)__shfl_xor((int)c7,32);
    u4v w0v, w1v;
    w0v[0] = hi ? sh2 : c0;  w0v[1] = hi ? sh3 : c1;
    w0v[2] = hi ? c2 : sh0;  w0v[3] = hi ? c3 : sh1;
    w1v[0] = hi ? sh6 : c4;  w1v[1] = hi ? sh7 : c5;
    w1v[2] = hi ? c6 : sh4;  w1v[3] = hi ? c7 : sh5;
    bf8v pa0 = __builtin_bit_cast(bf8v, w0v);   // P[q=l5][k = hi*8+j]
    bf8v pa1 = __builtin_bit_cast(bf8v, w1v);   // P[q=l5][k = 16+hi*8+j]

    // ---- PV: O^T += V^T-frag x P-frag ----
    #pragma unroll
    for (int uc=0; uc<4; uc++){
      o[uc] = MFMA32(v0[uc], pa0, o[uc]);
      o[uc] = MFMA32(v1[uc], pa1, o[uc]);
    }

    asm volatile("" ::: "memory");
    __builtin_amdgcn_s_barrier();    // all waves done reading Kls[cur] before restage
    cur ^= 1;
  }

  // ---- epilogue: per-wave (q-rows disjoint) normalized partial + stats ----
  const size_t rowg = (size_t)(b*S_ + q0 + l5);
  if (hi==0){
    Mst[(size_t)s*BS_ + rowg] = mrow;
    Lst[(size_t)s*BS_ + rowg] = lrow;
  }
  float inv = 1.0f / lrow;
  bf16* Op = Opart + (size_t)s*BS_*U_ + rowg*U_;
  #pragma unroll
  for (int uc=0; uc<4; uc++){
    #pragma unroll
    for (int g2=0; g2<4; g2++){
      us4 outv;
      #pragma unroll
      for (int j=0;j<4;j++) outv[j] = f2bits(o[uc][g2*4+j]*inv);
      *reinterpret_cast<us4*>(Op + uc*32 + g2*8 + hi*4) = outv;
    }
  }
}

// ---------------- combine the KV splits ----------------
__global__ __launch_bounds__(256) void combine_kernel(const bf16* __restrict__ Opart,
                                                      const float* __restrict__ Mst,
                                                      const float* __restrict__ Lst,
                                                      bf16* __restrict__ O,
                                                      int nsplit){
  int idx = blockIdx.x*256 + threadIdx.x;   // BS*U/8 threads
  int row = idx >> 4;
  int uc8 = (idx & 15) * 8;
  float m0 = Mst[row];
  float m1 = (nsplit>1) ? Mst[BS_+row]   : -1e30f;
  float m2 = (nsplit>2) ? Mst[2*BS_+row] : -1e30f;
  float m3 = (nsplit>3) ? Mst[3*BS_+row] : -1e30f;
  float M  = fmaxf(fmaxf(m0,m1), fmaxf(m2,m3));
  float w0 = Lst[row]*__expf(m0-M);
  float w1 = (nsplit>1) ? Lst[BS_+row]*__expf(m1-M)   : 0.f;
  float w2 = (nsplit>2) ? Lst[2*BS_+row]*__expf(m2-M) : 0.f;
  float w3 = (nsplit>3) ? Lst[3*BS_+row]*__expf(m3-M) : 0.f;
  float inv = 1.0f/(w0+w1+w2+w3);
  const size_t off = (size_t)row*U_ + uc8;
  const unsigned short* Ou = reinterpret_cast<const unsigned short*>(Opart);
  float acc[8];
  us8 p0 = *reinterpret_cast<const us8*>(Ou + off);
  #pragma unroll
  for (int j=0;j<8;j++) acc[j] = w0*b2f(p0[j]);
  if (nsplit>1){
    us8 p1 = *reinterpret_cast<const us8*>(Ou + (size_t)BS_*U_ + off);
    #pragma unroll
    for (int j=0;j<8;j++) acc[j] += w1*b2f(p1[j]);
  }
  if (nsplit>2){
    us8 p2 = *reinterpret_cast<const us8*>(Ou + (size_t)2*BS_*U_ + off);
    #pragma unroll
    for (int j=0;j<8;j++) acc[j] += w2*b2f(p2[j]);
  }
  if (nsplit>3){
    us8 p3 = *reinterpret_cast<const us8*>(Ou + (size_t)3*BS_*U_ + off);
    #pragma unroll
    for (int j=0;j<8;j++) acc[j] += w3*b2f(p3[j]);
  }
  us8 outv;
  #pragma unroll
  for (int j=0;j<8;j++) outv[j] = f2bits(acc[j]*inv);
  *reinterpret_cast<us8*>(reinterpret_cast<unsigned short*>(O) + off) = outv;
}

// ---------------- output projection + residual ----------------
__global__ __launch_bounds__(256) void oproj_kernel(const bf16* __restrict__ O,
                                                    const bf16* __restrict__ Wot,
                                                    const float* __restrict__ X,
                                                    const float* __restrict__ bo,
                                                    float* __restrict__ Y){
  const int w    = threadIdx.x >> 6;
  const int lane = threadIdx.x & 63;
  const int lq   = lane & 15;
  const int g    = lane >> 4;
  const int m0   = blockIdx.x*64 + w*16;
  const int n0   = blockIdx.y*128;

  f4v acc[8];
  #pragma unroll
  for (int i=0;i<8;i++) acc[i] = (f4v){0.f,0.f,0.f,0.f};

  const bf16* op = O + (size_t)(m0+lq)*U_ + g*8;
  #pragma unroll
  for (int k0=0;k0<U_;k0+=32){
    bf8v a = *reinterpret_cast<const bf8v*>(op + k0);
    #pragma unroll
    for (int nc=0;nc<8;nc++){
      bf8v bb = *reinterpret_cast<const bf8v*>(Wot + (size_t)(n0+nc*16+lq)*U_ + k0 + g*8);
      acc[nc] = MFMA16(a, bb, acc[nc]);
    }
  }

  #pragma unroll
  for (int nc=0;nc<8;nc++){
    int col = n0 + nc*16 + lq;
    float bias = bo[col];
    #pragma unroll
    for (int r=0;r<4;r++){
      int row = m0 + g*4 + r;
      Y[(size_t)row*D_ + col] = acc[nc][r] + bias + X[(size_t)row*D_ + col];
    }
  }
}

extern "C" void kernel_launch(void* const* d_in, const int* in_sizes, int n_in,
                              void* d_out, int out_size, void* d_ws, size_t ws_size,
                              hipStream_t stream) {
  (void)in_sizes; (void)n_in; (void)out_size;
  const float* X  = (const float*)d_in[0];
  const float* Wq = (const float*)d_in[1];
  const float* Wk = (const float*)d_in[2];
  const float* Wv = (const float*)d_in[3];
  const float* Wo = (const float*)d_in[4];
  const float* bo = (const float*)d_in[5];
  float* Y = (float*)d_out;

  // choose split count by available scratch (deterministic per session)
  const size_t MB = 1u<<20;
  int nsplit = (ws_size >= 34340864u) ? 4 : ((ws_size >= 30015488u) ? 3 : 2);

  char* ws = (char*)d_ws;
  bf16* Opart = (bf16*)ws;                       // nsplit*4MB; first 8MB double as Xb
  bf16* Xb    = (bf16*)ws;                       // BS*D*2 = 8MB (dead after qkv)
  size_t off = (size_t)nsplit*4*MB;
  bf16* Qb  = (bf16*)(ws + off); off += 4*MB;
  bf16* Kb  = (bf16*)(ws + off); off += 4*MB;
  bf16* Vt  = (bf16*)(ws + off); off += 4*MB;
  bf16* Ob  = (bf16*)(ws + off); off += 4*MB;
  bf16* Wqt = (bf16*)(ws + off); off += 65536;
  bf16* Wkt = (bf16*)(ws + off); off += 65536;
  bf16* Wvt = (bf16*)(ws + off); off += 65536;
  bf16* Wot = (bf16*)(ws + off); off += 65536;
  float* Mst = (float*)(ws + off); off += (size_t)nsplit*BS_*4;
  float* Lst = (float*)(ws + off);

  convert_x_kernel<<<dim3(BS_*D_/4/256), dim3(256), 0, stream>>>(X, (unsigned short*)Xb);
  prep_w_kernel<<<dim3(512), dim3(256), 0, stream>>>(Wq, Wk, Wv, Wo, Wqt, Wkt, Wvt, Wot);
  qkv_kernel<<<dim3(BS_/64, 3), dim3(256), 0, stream>>>(Xb, Wqt, Wkt, Wvt, Qb, Kb, Vt);
  flash_kernel<<<dim3(16*nsplit*8), dim3(256), 0, stream>>>(Qb, Kb, Vt, Opart, Mst, Lst, nsplit);
  combine_kernel<<<dim3(BS_*U_/8/256), dim3(256), 0, stream>>>(Opart, Mst, Lst, Ob, nsplit);
  oproj_kernel<<<dim3(BS_/64, 2), dim3(256), 0, stream>>>(Ob, Wot, X, bo, Y);
}

// Round 8
// 109.110 us; speedup vs baseline: 1.2757x; 1.0017x over previous
//
#include <hip/hip_runtime.h>
#include <hip/hip_bf16.h>

#define B_ 8
#define S_ 2048
#define D_ 256
#define U_ 128
#define BS_ (B_*S_)

using bf16 = __hip_bfloat16;
typedef __attribute__((ext_vector_type(8))) __bf16 bf8v;      // MFMA A/B frag (4 VGPR)
typedef __attribute__((ext_vector_type(4))) float f4v;        // 16x16 C/D frag
typedef __attribute__((ext_vector_type(16))) float f16v;      // 32x32 C/D frag
typedef __attribute__((ext_vector_type(4))) float float4v;
typedef __attribute__((ext_vector_type(4))) unsigned short us4;
typedef __attribute__((ext_vector_type(8))) unsigned short us8;
typedef __attribute__((ext_vector_type(4))) unsigned int u4v;
typedef __attribute__((ext_vector_type(2))) unsigned int u2v;

#define MFMA16(a,b,c) __builtin_amdgcn_mfma_f32_16x16x32_bf16((a),(b),(c),0,0,0)
#define MFMA32(a,b,c) __builtin_amdgcn_mfma_f32_32x32x16_bf16((a),(b),(c),0,0,0)

#if __has_builtin(__builtin_amdgcn_exp2f)
#define EXP2(x) __builtin_amdgcn_exp2f(x)
#else
#define EXP2(x) exp2f(x)
#endif

__device__ __forceinline__ unsigned short f2bits(float f){
  return __builtin_bit_cast(unsigned short, __float2bfloat16(f));
}
__device__ __forceinline__ float b2f(unsigned short u){
  return __builtin_bit_cast(float, ((unsigned)u) << 16);
}

// permlane32_swap: returns a' = {a.lo32lanes, b.lo32lanes}, b' = {a.hi32lanes, b.hi32lanes}
// (i.e. swaps the upper 32 lanes of a with the lower 32 lanes of b).
// SSA builtin -> no register-aliasing hazard (raw asm with a==b coalesces registers!).
__device__ __forceinline__ void plswap(unsigned &a, unsigned &b){
#if __has_builtin(__builtin_amdgcn_permlane32_swap)
  u2v r = __builtin_amdgcn_permlane32_swap(a, b, 0, 0);
  a = r[0]; b = r[1];
#else
  unsigned as = (unsigned)__shfl_xor((int)a, 32);
  unsigned bs = (unsigned)__shfl_xor((int)b, 32);
  bool hi = (threadIdx.x & 32) != 0;
  unsigned na = hi ? bs : a;
  unsigned nb = hi ? b  : as;
  a = na; b = nb;
#endif
}
// cross-half (lane vs lane^32) max / sum via permlane32_swap
__device__ __forceinline__ float cross_max(float x){
  unsigned a = __builtin_bit_cast(unsigned, x), b = a;
  plswap(a, b);
  return fmaxf(__builtin_bit_cast(float, a), __builtin_bit_cast(float, b));
}
__device__ __forceinline__ float cross_sum(float x){
  unsigned a = __builtin_bit_cast(unsigned, x), b = a;
  plswap(a, b);
  return __builtin_bit_cast(float, a) + __builtin_bit_cast(float, b);
}

// async global->LDS, 16B per lane; LDS dest = wave-uniform base + lane*16
__device__ __forceinline__ void gload16(const void* g, void* l){
  __builtin_amdgcn_global_load_lds(
    (const __attribute__((address_space(1))) char*)(unsigned long long)g,
    (__attribute__((address_space(3))) char*)(unsigned int)(unsigned long long)l,
    16, 0, 0);
}

// ---------------- prep: weight transpose+convert ----------------
__global__ __launch_bounds__(256) void prep_w_kernel(const float* __restrict__ Wq,
                                                     const float* __restrict__ Wk,
                                                     const float* __restrict__ Wv,
                                                     const float* __restrict__ Wo,
                                                     bf16* __restrict__ Wqt,
                                                     bf16* __restrict__ Wkt,
                                                     bf16* __restrict__ Wvt,
                                                     bf16* __restrict__ Wot){
  int t = blockIdx.x*256 + threadIdx.x;             // 4*32768 threads
  int s = t >> 15;
  int idx = t & 32767;
  if (s < 3){
    const float* src = (s==0)?Wq:((s==1)?Wk:Wv);
    bf16* dst = (s==0)?Wqt:((s==1)?Wkt:Wvt);
    int u = idx >> 8;          // /D_ = 256
    int d = idx & 255;
    dst[(size_t)u*D_ + d] = __float2bfloat16(src[(size_t)d*U_ + u]);
  } else {
    int dd = idx >> 7;         // /U_ = 128
    int u  = idx & 127;
    Wot[(size_t)dd*U_ + u] = __float2bfloat16(Wo[(size_t)u*D_ + dd]);
  }
}

// ---------------- QKV projection GEMM (reads X fp32, converts inline) ----------------
// Q is pre-scaled by log2(e)/sqrt(U) so softmax can use native exp2.
__global__ __launch_bounds__(256) void qkv_kernel(const float* __restrict__ X,
                                                  const bf16* __restrict__ Wqt,
                                                  const bf16* __restrict__ Wkt,
                                                  const bf16* __restrict__ Wvt,
                                                  bf16* __restrict__ Q,
                                                  bf16* __restrict__ K,
                                                  bf16* __restrict__ Vt){
  const int which = blockIdx.y;
  const bf16* Wt = (which==0) ? Wqt : ((which==1) ? Wkt : Wvt);
  const int w    = threadIdx.x >> 6;
  const int lane = threadIdx.x & 63;
  const int lq   = lane & 15;
  const int g    = lane >> 4;
  const int m0   = blockIdx.x*64 + w*16;

  f4v acc[8];
  #pragma unroll
  for (int i=0;i<8;i++) acc[i] = (f4v){0.f,0.f,0.f,0.f};

  const float* xp = X + (size_t)(m0+lq)*D_ + g*8;
  #pragma unroll
  for (int k0=0;k0<D_;k0+=32){
    float4v x0 = *reinterpret_cast<const float4v*>(xp + k0);
    float4v x1 = *reinterpret_cast<const float4v*>(xp + k0 + 4);
    us8 av;
    #pragma unroll
    for (int j=0;j<4;j++){ av[j] = f2bits(x0[j]); av[4+j] = f2bits(x1[j]); }
    bf8v a = __builtin_bit_cast(bf8v, av);
    #pragma unroll
    for (int nc=0;nc<8;nc++){
      bf8v b = *reinterpret_cast<const bf8v*>(Wt + (size_t)(nc*16+lq)*D_ + k0 + g*8);
      acc[nc] = MFMA16(a, b, acc[nc]);
    }
  }

  if (which==0){
    const float qscale = 0.12751745562008530f;      // log2(e)/sqrt(U)
    #pragma unroll
    for (int nc=0;nc<8;nc++){
      #pragma unroll
      for (int r=0;r<4;r++){
        Q[(size_t)(m0+g*4+r)*U_ + nc*16+lq] = __float2bfloat16(acc[nc][r]*qscale);
      }
    }
  } else if (which==1){
    #pragma unroll
    for (int nc=0;nc<8;nc++){
      #pragma unroll
      for (int r=0;r<4;r++){
        K[(size_t)(m0+g*4+r)*U_ + nc*16+lq] = __float2bfloat16(acc[nc][r]);
      }
    }
  } else {
    #pragma unroll
    for (int nc=0;nc<8;nc++){
      #pragma unroll
      for (int r=0;r<4;r++){
        int m = m0 + g*4 + r;
        int b = m >> 11;               // /S_
        int s = m & (S_-1);
        Vt[((size_t)b*U_ + nc*16+lq)*S_ + s] = __float2bfloat16(acc[nc][r]);
      }
    }
  }
}

// ---------------- flash attention: 64-k LDS-staged tiles, 32x32 MFMA ----------------
// grid = 16*nsplit*8 blocks x 256 thr (4 waves). blockIdx.x = (qt*nsplit+s)*8 + b.
// Each wave owns a different 32-q tile; all 4 waves share the staged K stream.
// K tile [64][128] bf16 double-buffered in LDS (global_load_lds, pre-swizzled src).
// Softmax in log2 domain (Q pre-scaled by log2e); cross-half ops via permlane32_swap.
__global__ __launch_bounds__(256) void flash_kernel(const bf16* __restrict__ Q,
                                                    const bf16* __restrict__ K,
                                                    const bf16* __restrict__ Vt,
                                                    bf16* __restrict__ Opart,
                                                    float* __restrict__ Mst,
                                                    float* __restrict__ Lst,
                                                    int nsplit){
  __shared__ bf16 Kls[2][64*128];      // 2 x 16KB

  const int n    = blockIdx.x;
  const int b    = n & 7;
  const int m    = n >> 3;
  const int s    = m % nsplit;
  const int qt   = m / nsplit;
  const int w    = threadIdx.x >> 6;
  const int lane = threadIdx.x & 63;
  const int l5   = lane & 31;
  const int hi   = lane >> 5;
  const int q0   = qt*128 + w*32;

  const int NT = S_/64;                // 32 big tiles
  const int t0 = (s*NT)/nsplit;
  const int t1 = ((s+1)*NT)/nsplit;

  // Q B-frags (pre-scaled): lane holds Q[q0+l5][uc*16 + hi*8 + j]
  const bf16* Qp = Q + (size_t)(b*S_ + q0 + l5)*U_ + hi*8;
  bf8v qf[8];
  #pragma unroll
  for (int uc=0; uc<8; uc++) qf[uc] = *reinterpret_cast<const bf8v*>(Qp + uc*16);

  f16v o[4];
  #pragma unroll
  for (int uc=0; uc<4; uc++)
    #pragma unroll
    for (int r=0; r<16; r++) o[uc][r] = 0.f;

  float mrow = -1e30f, lrow = 0.f;

  const bf16* Vb    = Vt + ((size_t)b*U_ + l5)*S_ + hi*8;
  const bf16* Kbase = K + (size_t)b*S_*U_;

  // stage 64-row K tile t into buffer buf: wave w covers rows [w*16, w*16+16)
  auto stage = [&](int buf, int t){
    const int r0 = w*16;
    #pragma unroll
    for (int c=0; c<4; c++){
      int row  = r0 + c*4 + (lane>>4);
      int soff = ((lane&15)<<4) ^ ((row&7)<<4);
      const char* src = (const char*)(Kbase + (size_t)(t*64 + row)*U_) + soff;
      gload16(src, (void*)&Kls[buf][(r0 + c*4)*128]);
    }
  };

  stage(0, t0);
  int cur = 0;
  for (int tt=t0; tt<t1; ++tt){
    int tn = (tt+1 < NT) ? (tt+1) : (NT-1);
    stage(cur^1, tn);                                  // 4 vmem ops in flight for t+1
    asm volatile("s_waitcnt vmcnt(4)" ::: "memory");   // tile tt staged
    __builtin_amdgcn_s_barrier();
    unsigned bufoff = (unsigned)cur * 16384u;          // launder: pin LDS reads after barrier
    asm volatile("" : "+v"(bufoff) : : "memory");
    const char* kb0 = (const char*)&Kls[0][0] + bufoff;

    #pragma unroll
    for (int sub=0; sub<2; ++sub){
      const char* kb = kb0 + sub*8192;

      // V prefetch (global, L1-shared across waves)
      const bf16* vp = Vb + tt*64 + sub*32;
      bf8v v0[4], v1[4];
      #pragma unroll
      for (int uc=0; uc<4; uc++){
        v0[uc] = *reinterpret_cast<const bf8v*>(vp + (size_t)(uc*32)*S_);
        v1[uc] = *reinterpret_cast<const bf8v*>(vp + (size_t)(uc*32)*S_ + 16);
      }

      // ---- QK^T from LDS (swizzled reads) ----
      f16v st0, st1;
      #pragma unroll
      for (int r=0;r<16;r++){ st0[r]=0.f; st1[r]=0.f; }
      __builtin_amdgcn_s_setprio(1);
      #pragma unroll
      for (int uc=0; uc<4; uc++){
        bf8v ka = *reinterpret_cast<const bf8v*>(kb + l5*256 + ((uc*64      + hi*16) ^ ((l5&7)<<4)));
        bf8v kc = *reinterpret_cast<const bf8v*>(kb + l5*256 + ((uc*64 + 32 + hi*16) ^ ((l5&7)<<4)));
        st0 = MFMA32(ka, qf[2*uc],   st0);
        st1 = MFMA32(kc, qf[2*uc+1], st1);
      }
      __builtin_amdgcn_s_setprio(0);
      float p[16];
      #pragma unroll
      for (int r=0;r<16;r++) p[r] = st0[r] + st1[r];

      // ---- softmax stats (log2 domain; lane-local col q=l5) ----
      float a0 = fmaxf(p[0],p[1]),  a1 = fmaxf(p[2],p[3]);
      float a2 = fmaxf(p[4],p[5]),  a3 = fmaxf(p[6],p[7]);
      float a4 = fmaxf(p[8],p[9]),  a5 = fmaxf(p[10],p[11]);
      float a6 = fmaxf(p[12],p[13]),a7 = fmaxf(p[14],p[15]);
      float b0 = fmaxf(a0,a1), b1 = fmaxf(a2,a3), b2 = fmaxf(a4,a5), b3 = fmaxf(a6,a7);
      float tm = fmaxf(fmaxf(b0,b1), fmaxf(b2,b3));
      tm = cross_max(tm);

      if (!__all(tm <= mrow + 11.54f)){        // defer-max (8 nats in log2)
        float mn    = fmaxf(mrow, tm);
        float alpha = EXP2(mrow - mn);
        lrow *= alpha;
        #pragma unroll
        for (int uc=0;uc<4;uc++)
          #pragma unroll
          for (int r=0;r<16;r++) o[uc][r] *= alpha;
        mrow = mn;
      }

      #pragma unroll
      for (int r=0;r<16;r++) p[r] = EXP2(p[r]-mrow);
      float s0s = (p[0]+p[1]) + (p[2]+p[3]);
      float s1s = (p[4]+p[5]) + (p[6]+p[7]);
      float s2s = (p[8]+p[9]) + (p[10]+p[11]);
      float s3s = (p[12]+p[13]) + (p[14]+p[15]);
      lrow += cross_sum((s0s+s1s) + (s2s+s3s));

      // ---- P -> bf16 A-frags via permlane32_swap ----
      // lane's p[r] = P[q=l5][k=(r&3)+8*(r>>2)+4*hi]
      unsigned c0 = (unsigned)f2bits(p[0])  | ((unsigned)f2bits(p[1])<<16);
      unsigned c1 = (unsigned)f2bits(p[2])  | ((unsigned)f2bits(p[3])<<16);
      unsigned c2 = (unsigned)f2bits(p[4])  | ((unsigned)f2bits(p[5])<<16);
      unsigned c3 = (unsigned)f2bits(p[6])  | ((unsigned)f2bits(p[7])<<16);
      unsigned c4 = (unsigned)f2bits(p[8])  | ((unsigned)f2bits(p[9])<<16);
      unsigned c5 = (unsigned)f2bits(p[10]) | ((unsigned)f2bits(p[11])<<16);
      unsigned c6 = (unsigned)f2bits(p[12]) | ((unsigned)f2bits(p[13])<<16);
      unsigned c7 = (unsigned)f2bits(p[14]) | ((unsigned)f2bits(p[15])<<16);
      plswap(c0, c2);   // c0' = {c0.lo, c2.lo}, c2' = {c0.hi, c2.hi}
      plswap(c1, c3);
      plswap(c4, c6);
      plswap(c5, c7);
      u4v w0v = {c0, c1, c2, c3};
      u4v w1v = {c4, c5, c6, c7};
      bf8v pa0 = __builtin_bit_cast(bf8v, w0v);   // P[q=l5][k = hi*8+j]
      bf8v pa1 = __builtin_bit_cast(bf8v, w1v);   // P[q=l5][k = 16+hi*8+j]

      // ---- PV: O^T += V^T-frag x P-frag ----
      __builtin_amdgcn_s_setprio(1);
      #pragma unroll
      for (int uc=0; uc<4; uc++){
        o[uc] = MFMA32(v0[uc], pa0, o[uc]);
        o[uc] = MFMA32(v1[uc], pa1, o[uc]);
      }
      __builtin_amdgcn_s_setprio(0);
    }

    asm volatile("" ::: "memory");
    __builtin_amdgcn_s_barrier();    // all waves done reading Kls[cur] before restage
    cur ^= 1;
  }

  // ---- epilogue: per-wave (q-rows disjoint) normalized partial + stats ----
  const size_t rowg = (size_t)(b*S_ + q0 + l5);
  if (hi==0){
    Mst[(size_t)s*BS_ + rowg] = mrow;
    Lst[(size_t)s*BS_ + rowg] = lrow;
  }
  float inv = 1.0f / lrow;
  bf16* Op = Opart + (size_t)s*BS_*U_ + rowg*U_;
  #pragma unroll
  for (int uc=0; uc<4; uc++){
    #pragma unroll
    for (int g2=0; g2<4; g2++){
      us4 outv;
      #pragma unroll
      for (int j=0;j<4;j++) outv[j] = f2bits(o[uc][g2*4+j]*inv);
      *reinterpret_cast<us4*>(Op + uc*32 + g2*8 + hi*4) = outv;
    }
  }
}

// ---------------- combine the KV splits (log2-domain stats) ----------------
__global__ __launch_bounds__(256) void combine_kernel(const bf16* __restrict__ Opart,
                                                      const float* __restrict__ Mst,
                                                      const float* __restrict__ Lst,
                                                      bf16* __restrict__ O,
                                                      int nsplit){
  int idx = blockIdx.x*256 + threadIdx.x;   // BS*U/8 threads
  int row = idx >> 4;
  int uc8 = (idx & 15) * 8;
  float m0 = Mst[row];
  float m1 = (nsplit>1) ? Mst[BS_+row]   : -1e30f;
  float m2 = (nsplit>2) ? Mst[2*BS_+row] : -1e30f;
  float m3 = (nsplit>3) ? Mst[3*BS_+row] : -1e30f;
  float M  = fmaxf(fmaxf(m0,m1), fmaxf(m2,m3));
  float w0 = Lst[row]*EXP2(m0-M);
  float w1 = (nsplit>1) ? Lst[BS_+row]*EXP2(m1-M)   : 0.f;
  float w2 = (nsplit>2) ? Lst[2*BS_+row]*EXP2(m2-M) : 0.f;
  float w3 = (nsplit>3) ? Lst[3*BS_+row]*EXP2(m3-M) : 0.f;
  float inv = 1.0f/(w0+w1+w2+w3);
  const size_t off = (size_t)row*U_ + uc8;
  const unsigned short* Ou = reinterpret_cast<const unsigned short*>(Opart);
  float acc[8];
  us8 p0 = *reinterpret_cast<const us8*>(Ou + off);
  #pragma unroll
  for (int j=0;j<8;j++) acc[j] = w0*b2f(p0[j]);
  if (nsplit>1){
    us8 p1 = *reinterpret_cast<const us8*>(Ou + (size_t)BS_*U_ + off);
    #pragma unroll
    for (int j=0;j<8;j++) acc[j] += w1*b2f(p1[j]);
  }
  if (nsplit>2){
    us8 p2 = *reinterpret_cast<const us8*>(Ou + (size_t)2*BS_*U_ + off);
    #pragma unroll
    for (int j=0;j<8;j++) acc[j] += w2*b2f(p2[j]);
  }
  if (nsplit>3){
    us8 p3 = *reinterpret_cast<const us8*>(Ou + (size_t)3*BS_*U_ + off);
    #pragma unroll
    for (int j=0;j<8;j++) acc[j] += w3*b2f(p3[j]);
  }
  us8 outv;
  #pragma unroll
  for (int j=0;j<8;j++) outv[j] = f2bits(acc[j]*inv);
  *reinterpret_cast<us8*>(reinterpret_cast<unsigned short*>(O) + off) = outv;
}

// ---------------- output projection + residual ----------------
__global__ __launch_bounds__(256) void oproj_kernel(const bf16* __restrict__ O,
                                                    const bf16* __restrict__ Wot,
                                                    const float* __restrict__ X,
                                                    const float* __restrict__ bo,
                                                    float* __restrict__ Y){
  const int w    = threadIdx.x >> 6;
  const int lane = threadIdx.x & 63;
  const int lq   = lane & 15;
  const int g    = lane >> 4;
  const int m0   = blockIdx.x*64 + w*16;
  const int n0   = blockIdx.y*128;

  f4v acc[8];
  #pragma unroll
  for (int i=0;i<8;i++) acc[i] = (f4v){0.f,0.f,0.f,0.f};

  const bf16* op = O + (size_t)(m0+lq)*U_ + g*8;
  #pragma unroll
  for (int k0=0;k0<U_;k0+=32){
    bf8v a = *reinterpret_cast<const bf8v*>(op + k0);
    #pragma unroll
    for (int nc=0;nc<8;nc++){
      bf8v bb = *reinterpret_cast<const bf8v*>(Wot + (size_t)(n0+nc*16+lq)*U_ + k0 + g*8);
      acc[nc] = MFMA16(a, bb, acc[nc]);
    }
  }

  #pragma unroll
  for (int nc=0;nc<8;nc++){
    int col = n0 + nc*16 + lq;
    float bias = bo[col];
    #pragma unroll
    for (int r=0;r<4;r++){
      int row = m0 + g*4 + r;
      Y[(size_t)row*D_ + col] = acc[nc][r] + bias + X[(size_t)row*D_ + col];
    }
  }
}

extern "C" void kernel_launch(void* const* d_in, const int* in_sizes, int n_in,
                              void* d_out, int out_size, void* d_ws, size_t ws_size,
                              hipStream_t stream) {
  (void)in_sizes; (void)n_in; (void)out_size;
  const float* X  = (const float*)d_in[0];
  const float* Wq = (const float*)d_in[1];
  const float* Wk = (const float*)d_in[2];
  const float* Wv = (const float*)d_in[3];
  const float* Wo = (const float*)d_in[4];
  const float* bo = (const float*)d_in[5];
  float* Y = (float*)d_out;

  const size_t MB = 1u<<20;
  int nsplit = (ws_size >= 34340864u) ? 4 : ((ws_size >= 30015488u) ? 3 : 2);

  char* ws = (char*)d_ws;
  bf16* Opart = (bf16*)ws;                       // nsplit*4MB
  size_t off = (size_t)nsplit*4*MB;
  bf16* Qb  = (bf16*)(ws + off); off += 4*MB;
  bf16* Kb  = (bf16*)(ws + off); off += 4*MB;
  bf16* Vt  = (bf16*)(ws + off); off += 4*MB;
  bf16* Ob  = (bf16*)(ws + off); off += 4*MB;
  bf16* Wqt = (bf16*)(ws + off); off += 65536;
  bf16* Wkt = (bf16*)(ws + off); off += 65536;
  bf16* Wvt = (bf16*)(ws + off); off += 65536;
  bf16* Wot = (bf16*)(ws + off); off += 65536;
  float* Mst = (float*)(ws + off); off += (size_t)nsplit*BS_*4;
  float* Lst = (float*)(ws + off);

  prep_w_kernel<<<dim3(512), dim3(256), 0, stream>>>(Wq, Wk, Wv, Wo, Wqt, Wkt, Wvt, Wot);
  qkv_kernel<<<dim3(BS_/64, 3), dim3(256), 0, stream>>>(X, Wqt, Wkt, Wvt, Qb, Kb, Vt);
  flash_kernel<<<dim3(16*nsplit*8), dim3(256), 0, stream>>>(Qb, Kb, Vt, Opart, Mst, Lst, nsplit);
  combine_kernel<<<dim3(BS_*U_/8/256), dim3(256), 0, stream>>>(Opart, Mst, Lst, Ob, nsplit);
  oproj_kernel<<<dim3(BS_/64, 2), dim3(256), 0, stream>>>(Ob, Wot, X, bo, Y);
}

// Round 9
// 96.794 us; speedup vs baseline: 1.4381x; 1.1272x over previous
//
#include <hip/hip_runtime.h>
#include <hip/hip_bf16.h>

#define B_ 8
#define S_ 2048
#define D_ 256
#define U_ 128
#define BS_ (B_*S_)

using bf16 = __hip_bfloat16;
typedef __attribute__((ext_vector_type(8))) __bf16 bf8v;      // MFMA A/B frag (4 VGPR)
typedef __attribute__((ext_vector_type(4))) float f4v;        // 16x16 C/D frag
typedef __attribute__((ext_vector_type(16))) float f16v;      // 32x32 C/D frag
typedef __attribute__((ext_vector_type(4))) float float4v;
typedef __attribute__((ext_vector_type(4))) unsigned short us4;
typedef __attribute__((ext_vector_type(8))) unsigned short us8;
typedef __attribute__((ext_vector_type(4))) unsigned int u4v;
typedef __attribute__((ext_vector_type(2))) unsigned int u2v;

#define MFMA16(a,b,c) __builtin_amdgcn_mfma_f32_16x16x32_bf16((a),(b),(c),0,0,0)
#define MFMA32(a,b,c) __builtin_amdgcn_mfma_f32_32x32x16_bf16((a),(b),(c),0,0,0)

#if __has_builtin(__builtin_amdgcn_exp2f)
#define EXP2(x) __builtin_amdgcn_exp2f(x)
#else
#define EXP2(x) exp2f(x)
#endif

__device__ __forceinline__ unsigned short f2bits(float f){
  return __builtin_bit_cast(unsigned short, __float2bfloat16(f));
}
__device__ __forceinline__ float b2f(unsigned short u){
  return __builtin_bit_cast(float, ((unsigned)u) << 16);
}

// permlane32_swap (SSA builtin -> no register-aliasing hazard)
__device__ __forceinline__ void plswap(unsigned &a, unsigned &b){
#if __has_builtin(__builtin_amdgcn_permlane32_swap)
  u2v r = __builtin_amdgcn_permlane32_swap(a, b, 0, 0);
  a = r[0]; b = r[1];
#else
  unsigned as = (unsigned)__shfl_xor((int)a, 32);
  unsigned bs = (unsigned)__shfl_xor((int)b, 32);
  bool hi = (threadIdx.x & 32) != 0;
  unsigned na = hi ? bs : a;
  unsigned nb = hi ? b  : as;
  a = na; b = nb;
#endif
}
__device__ __forceinline__ float cross_max(float x){
  unsigned a = __builtin_bit_cast(unsigned, x), b = a;
  plswap(a, b);
  return fmaxf(__builtin_bit_cast(float, a), __builtin_bit_cast(float, b));
}
__device__ __forceinline__ float cross_sum(float x){
  unsigned a = __builtin_bit_cast(unsigned, x), b = a;
  plswap(a, b);
  return __builtin_bit_cast(float, a) + __builtin_bit_cast(float, b);
}

// async global->LDS, 16B per lane; LDS dest = wave-uniform base + lane*16
__device__ __forceinline__ void gload16(const void* g, void* l){
  __builtin_amdgcn_global_load_lds(
    (const __attribute__((address_space(1))) char*)(unsigned long long)g,
    (__attribute__((address_space(3))) char*)(unsigned int)(unsigned long long)l,
    16, 0, 0);
}

// ---------------- prep: weight transpose+convert ----------------
__global__ __launch_bounds__(256) void prep_w_kernel(const float* __restrict__ Wq,
                                                     const float* __restrict__ Wk,
                                                     const float* __restrict__ Wv,
                                                     const float* __restrict__ Wo,
                                                     bf16* __restrict__ Wqt,
                                                     bf16* __restrict__ Wkt,
                                                     bf16* __restrict__ Wvt,
                                                     bf16* __restrict__ Wot){
  int t = blockIdx.x*256 + threadIdx.x;             // 4*32768 threads
  int s = t >> 15;
  int idx = t & 32767;
  if (s < 3){
    const float* src = (s==0)?Wq:((s==1)?Wk:Wv);
    bf16* dst = (s==0)?Wqt:((s==1)?Wkt:Wvt);
    int u = idx >> 8;          // /D_ = 256
    int d = idx & 255;
    dst[(size_t)u*D_ + d] = __float2bfloat16(src[(size_t)d*U_ + u]);
  } else {
    int dd = idx >> 7;         // /U_ = 128
    int u  = idx & 127;
    Wot[(size_t)dd*U_ + u] = __float2bfloat16(Wo[(size_t)u*D_ + dd]);
  }
}

// ---------------- QKV projection GEMM (reads X fp32, converts inline) ----------------
// Q is pre-scaled by log2(e)/sqrt(U) so softmax can use native exp2.
__global__ __launch_bounds__(256) void qkv_kernel(const float* __restrict__ X,
                                                  const bf16* __restrict__ Wqt,
                                                  const bf16* __restrict__ Wkt,
                                                  const bf16* __restrict__ Wvt,
                                                  bf16* __restrict__ Q,
                                                  bf16* __restrict__ K,
                                                  bf16* __restrict__ Vt){
  const int which = blockIdx.y;
  const bf16* Wt = (which==0) ? Wqt : ((which==1) ? Wkt : Wvt);
  const int w    = threadIdx.x >> 6;
  const int lane = threadIdx.x & 63;
  const int lq   = lane & 15;
  const int g    = lane >> 4;
  const int m0   = blockIdx.x*64 + w*16;

  f4v acc[8];
  #pragma unroll
  for (int i=0;i<8;i++) acc[i] = (f4v){0.f,0.f,0.f,0.f};

  const float* xp = X + (size_t)(m0+lq)*D_ + g*8;
  #pragma unroll
  for (int k0=0;k0<D_;k0+=32){
    float4v x0 = *reinterpret_cast<const float4v*>(xp + k0);
    float4v x1 = *reinterpret_cast<const float4v*>(xp + k0 + 4);
    us8 av;
    #pragma unroll
    for (int j=0;j<4;j++){ av[j] = f2bits(x0[j]); av[4+j] = f2bits(x1[j]); }
    bf8v a = __builtin_bit_cast(bf8v, av);
    #pragma unroll
    for (int nc=0;nc<8;nc++){
      bf8v b = *reinterpret_cast<const bf8v*>(Wt + (size_t)(nc*16+lq)*D_ + k0 + g*8);
      acc[nc] = MFMA16(a, b, acc[nc]);
    }
  }

  if (which==0){
    const float qscale = 0.12751745562008530f;      // log2(e)/sqrt(U)
    #pragma unroll
    for (int nc=0;nc<8;nc++){
      #pragma unroll
      for (int r=0;r<4;r++){
        Q[(size_t)(m0+g*4+r)*U_ + nc*16+lq] = __float2bfloat16(acc[nc][r]*qscale);
      }
    }
  } else if (which==1){
    #pragma unroll
    for (int nc=0;nc<8;nc++){
      #pragma unroll
      for (int r=0;r<4;r++){
        K[(size_t)(m0+g*4+r)*U_ + nc*16+lq] = __float2bfloat16(acc[nc][r]);
      }
    }
  } else {
    #pragma unroll
    for (int nc=0;nc<8;nc++){
      #pragma unroll
      for (int r=0;r<4;r++){
        int m = m0 + g*4 + r;
        int b = m >> 11;               // /S_
        int s = m & (S_-1);
        Vt[((size_t)b*U_ + nc*16+lq)*S_ + s] = __float2bfloat16(acc[nc][r]);
      }
    }
  }
}

// ---------------- flash attention: K AND V LDS-staged (coalesced), 32x32 MFMA ----------------
// grid = 16*nsplit*8 blocks x 256 thr (4 waves). blockIdx.x = (qt*nsplit+s)*8 + b.
// Each wave owns a different 32-q tile; 4 waves share staged K+V streams.
// K tile [64][128], V tile [128][64] (V^T rows coalesced 128B), both double-buffered,
// both XOR-swizzled (pre-swizzled global source + swizzled ds_read).
// ALL loop global traffic = gload_lds (vmcnt); ALL consumption = ds_read (lgkmcnt).
__global__ __launch_bounds__(256) void flash_kernel(const bf16* __restrict__ Q,
                                                    const bf16* __restrict__ K,
                                                    const bf16* __restrict__ Vt,
                                                    bf16* __restrict__ Opart,
                                                    float* __restrict__ Mst,
                                                    float* __restrict__ Lst,
                                                    int nsplit){
  __shared__ bf16 Kls[2][64*128];      // 2 x 16KB
  __shared__ bf16 Vls[2][128*64];      // 2 x 16KB

  const int n    = blockIdx.x;
  const int b    = n & 7;
  const int m    = n >> 3;
  const int s    = m % nsplit;
  const int qt   = m / nsplit;
  const int w    = threadIdx.x >> 6;
  const int lane = threadIdx.x & 63;
  const int l5   = lane & 31;
  const int hi   = lane >> 5;
  const int q0   = qt*128 + w*32;

  const int NT = S_/64;                // 32 big tiles
  const int t0 = (s*NT)/nsplit;
  const int t1 = ((s+1)*NT)/nsplit;

  // Q B-frags (pre-scaled): lane holds Q[q0+l5][uc*16 + hi*8 + j]
  const bf16* Qp = Q + (size_t)(b*S_ + q0 + l5)*U_ + hi*8;
  bf8v qf[8];
  #pragma unroll
  for (int uc=0; uc<8; uc++) qf[uc] = *reinterpret_cast<const bf8v*>(Qp + uc*16);

  f16v o[4];
  #pragma unroll
  for (int uc=0; uc<4; uc++)
    #pragma unroll
    for (int r=0; r<16; r++) o[uc][r] = 0.f;

  float mrow = -1e30f, lrow = 0.f;

  const bf16* Kbase = K  + (size_t)b*S_*U_;
  const bf16* Vtb   = Vt + (size_t)b*U_*S_;     // row u, stride S_

  // stage K tile t (rows = k, 256B each): wave w covers k-rows [w*16, w*16+16)
  auto stageK = [&](int buf, int t){
    const int r0 = w*16;
    #pragma unroll
    for (int c=0; c<4; c++){
      int row  = r0 + c*4 + (lane>>4);
      int soff = ((lane&15)<<4) ^ ((row&7)<<4);
      const char* src = (const char*)(Kbase + (size_t)(t*64 + row)*U_) + soff;
      gload16(src, (void*)&Kls[buf][(r0 + c*4)*128]);
    }
  };
  // stage V tile t (rows = u, 128B each = 64 k): wave w covers u-rows [w*32, w*32+32)
  auto stageV = [&](int buf, int t){
    const int r0 = w*32;
    #pragma unroll
    for (int c=0; c<4; c++){
      int u    = r0 + c*8 + (lane>>3);
      int soff = ((lane&7)<<4) ^ ((u&7)<<4);
      const char* src = (const char*)(Vtb + (size_t)u*S_ + t*64) + soff;
      gload16(src, (void*)&Vls[buf][(r0 + c*8)*64]);
    }
  };

  stageK(0, t0); stageV(0, t0);
  int cur = 0;
  for (int tt=t0; tt<t1; ++tt){
    int tn = (tt+1 < NT) ? (tt+1) : (NT-1);
    stageK(cur^1, tn); stageV(cur^1, tn);              // 8 vmem in flight for t+1
    asm volatile("s_waitcnt vmcnt(8)" ::: "memory");   // tile tt fully staged
    __builtin_amdgcn_s_barrier();
    unsigned bufoff = (unsigned)cur * 16384u;          // launder: pin LDS reads after barrier
    asm volatile("" : "+v"(bufoff) : : "memory");
    const char* kb0 = (const char*)&Kls[0][0] + bufoff;
    const char* vb0 = (const char*)&Vls[0][0] + bufoff;

    #pragma unroll
    for (int sub=0; sub<2; ++sub){
      const char* kb = kb0 + sub*8192;

      // ---- QK^T from LDS (swizzled reads) ----
      f16v st0, st1;
      #pragma unroll
      for (int r=0;r<16;r++){ st0[r]=0.f; st1[r]=0.f; }
      __builtin_amdgcn_s_setprio(1);
      #pragma unroll
      for (int uc=0; uc<4; uc++){
        bf8v ka = *reinterpret_cast<const bf8v*>(kb + l5*256 + ((uc*64      + hi*16) ^ ((l5&7)<<4)));
        bf8v kc = *reinterpret_cast<const bf8v*>(kb + l5*256 + ((uc*64 + 32 + hi*16) ^ ((l5&7)<<4)));
        st0 = MFMA32(ka, qf[2*uc],   st0);
        st1 = MFMA32(kc, qf[2*uc+1], st1);
      }
      __builtin_amdgcn_s_setprio(0);
      float p[16];
      #pragma unroll
      for (int r=0;r<16;r++) p[r] = st0[r] + st1[r];

      // ---- softmax stats (log2 domain; lane-local col q=l5) ----
      float a0 = fmaxf(p[0],p[1]),  a1 = fmaxf(p[2],p[3]);
      float a2 = fmaxf(p[4],p[5]),  a3 = fmaxf(p[6],p[7]);
      float a4 = fmaxf(p[8],p[9]),  a5 = fmaxf(p[10],p[11]);
      float a6 = fmaxf(p[12],p[13]),a7 = fmaxf(p[14],p[15]);
      float b0 = fmaxf(a0,a1), b1 = fmaxf(a2,a3), b2 = fmaxf(a4,a5), b3 = fmaxf(a6,a7);
      float tm = fmaxf(fmaxf(b0,b1), fmaxf(b2,b3));
      tm = cross_max(tm);

      if (!__all(tm <= mrow + 11.54f)){        // defer-max (8 nats in log2)
        float mn    = fmaxf(mrow, tm);
        float alpha = EXP2(mrow - mn);
        lrow *= alpha;
        #pragma unroll
        for (int uc=0;uc<4;uc++)
          #pragma unroll
          for (int r=0;r<16;r++) o[uc][r] *= alpha;
        mrow = mn;
      }

      #pragma unroll
      for (int r=0;r<16;r++) p[r] = EXP2(p[r]-mrow);
      float s0s = (p[0]+p[1]) + (p[2]+p[3]);
      float s1s = (p[4]+p[5]) + (p[6]+p[7]);
      float s2s = (p[8]+p[9]) + (p[10]+p[11]);
      float s3s = (p[12]+p[13]) + (p[14]+p[15]);
      lrow += cross_sum((s0s+s1s) + (s2s+s3s));

      // ---- P -> bf16 A-frags via permlane32_swap ----
      unsigned c0 = (unsigned)f2bits(p[0])  | ((unsigned)f2bits(p[1])<<16);
      unsigned c1 = (unsigned)f2bits(p[2])  | ((unsigned)f2bits(p[3])<<16);
      unsigned c2 = (unsigned)f2bits(p[4])  | ((unsigned)f2bits(p[5])<<16);
      unsigned c3 = (unsigned)f2bits(p[6])  | ((unsigned)f2bits(p[7])<<16);
      unsigned c4 = (unsigned)f2bits(p[8])  | ((unsigned)f2bits(p[9])<<16);
      unsigned c5 = (unsigned)f2bits(p[10]) | ((unsigned)f2bits(p[11])<<16);
      unsigned c6 = (unsigned)f2bits(p[12]) | ((unsigned)f2bits(p[13])<<16);
      unsigned c7 = (unsigned)f2bits(p[14]) | ((unsigned)f2bits(p[15])<<16);
      plswap(c0, c2);
      plswap(c1, c3);
      plswap(c4, c6);
      plswap(c5, c7);
      u4v w0v = {c0, c1, c2, c3};
      u4v w1v = {c4, c5, c6, c7};
      bf8v pa0 = __builtin_bit_cast(bf8v, w0v);   // P[q=l5][k = hi*8+j]
      bf8v pa1 = __builtin_bit_cast(bf8v, w1v);   // P[q=l5][k = 16+hi*8+j]

      // ---- PV from LDS V (swizzled reads): O^T += V^T-frag x P-frag ----
      __builtin_amdgcn_s_setprio(1);
      #pragma unroll
      for (int uc=0; uc<4; uc++){
        const char* vrow = vb0 + (uc*32 + l5)*128;
        bf8v v0 = *reinterpret_cast<const bf8v*>(vrow + ((sub*64      + hi*16) ^ ((l5&7)<<4)));
        bf8v v1 = *reinterpret_cast<const bf8v*>(vrow + ((sub*64 + 32 + hi*16) ^ ((l5&7)<<4)));
        o[uc] = MFMA32(v0, pa0, o[uc]);
        o[uc] = MFMA32(v1, pa1, o[uc]);
      }
      __builtin_amdgcn_s_setprio(0);
    }

    asm volatile("" ::: "memory");
    __builtin_amdgcn_s_barrier();    // all waves done reading buffers before restage
    cur ^= 1;
  }

  // ---- epilogue: per-wave (q-rows disjoint) normalized partial + stats ----
  const size_t rowg = (size_t)(b*S_ + q0 + l5);
  if (hi==0){
    Mst[(size_t)s*BS_ + rowg] = mrow;
    Lst[(size_t)s*BS_ + rowg] = lrow;
  }
  float inv = 1.0f / lrow;
  bf16* Op = Opart + (size_t)s*BS_*U_ + rowg*U_;
  #pragma unroll
  for (int uc=0; uc<4; uc++){
    #pragma unroll
    for (int g2=0; g2<4; g2++){
      us4 outv;
      #pragma unroll
      for (int j=0;j<4;j++) outv[j] = f2bits(o[uc][g2*4+j]*inv);
      *reinterpret_cast<us4*>(Op + uc*32 + g2*8 + hi*4) = outv;
    }
  }
}

// ---------------- combine the KV splits (log2-domain stats) ----------------
__global__ __launch_bounds__(256) void combine_kernel(const bf16* __restrict__ Opart,
                                                      const float* __restrict__ Mst,
                                                      const float* __restrict__ Lst,
                                                      bf16* __restrict__ O,
                                                      int nsplit){
  int idx = blockIdx.x*256 + threadIdx.x;   // BS*U/8 threads
  int row = idx >> 4;
  int uc8 = (idx & 15) * 8;
  float m0 = Mst[row];
  float m1 = (nsplit>1) ? Mst[BS_+row]   : -1e30f;
  float m2 = (nsplit>2) ? Mst[2*BS_+row] : -1e30f;
  float m3 = (nsplit>3) ? Mst[3*BS_+row] : -1e30f;
  float M  = fmaxf(fmaxf(m0,m1), fmaxf(m2,m3));
  float w0 = Lst[row]*EXP2(m0-M);
  float w1 = (nsplit>1) ? Lst[BS_+row]*EXP2(m1-M)   : 0.f;
  float w2 = (nsplit>2) ? Lst[2*BS_+row]*EXP2(m2-M) : 0.f;
  float w3 = (nsplit>3) ? Lst[3*BS_+row]*EXP2(m3-M) : 0.f;
  float inv = 1.0f/(w0+w1+w2+w3);
  const size_t off = (size_t)row*U_ + uc8;
  const unsigned short* Ou = reinterpret_cast<const unsigned short*>(Opart);
  float acc[8];
  us8 p0 = *reinterpret_cast<const us8*>(Ou + off);
  #pragma unroll
  for (int j=0;j<8;j++) acc[j] = w0*b2f(p0[j]);
  if (nsplit>1){
    us8 p1 = *reinterpret_cast<const us8*>(Ou + (size_t)BS_*U_ + off);
    #pragma unroll
    for (int j=0;j<8;j++) acc[j] += w1*b2f(p1[j]);
  }
  if (nsplit>2){
    us8 p2 = *reinterpret_cast<const us8*>(Ou + (size_t)2*BS_*U_ + off);
    #pragma unroll
    for (int j=0;j<8;j++) acc[j] += w2*b2f(p2[j]);
  }
  if (nsplit>3){
    us8 p3 = *reinterpret_cast<const us8*>(Ou + (size_t)3*BS_*U_ + off);
    #pragma unroll
    for (int j=0;j<8;j++) acc[j] += w3*b2f(p3[j]);
  }
  us8 outv;
  #pragma unroll
  for (int j=0;j<8;j++) outv[j] = f2bits(acc[j]*inv);
  *reinterpret_cast<us8*>(reinterpret_cast<unsigned short*>(O) + off) = outv;
}

// ---------------- output projection + residual ----------------
__global__ __launch_bounds__(256) void oproj_kernel(const bf16* __restrict__ O,
                                                    const bf16* __restrict__ Wot,
                                                    const float* __restrict__ X,
                                                    const float* __restrict__ bo,
                                                    float* __restrict__ Y){
  const int w    = threadIdx.x >> 6;
  const int lane = threadIdx.x & 63;
  const int lq   = lane & 15;
  const int g    = lane >> 4;
  const int m0   = blockIdx.x*64 + w*16;
  const int n0   = blockIdx.y*128;

  f4v acc[8];
  #pragma unroll
  for (int i=0;i<8;i++) acc[i] = (f4v){0.f,0.f,0.f,0.f};

  const bf16* op = O + (size_t)(m0+lq)*U_ + g*8;
  #pragma unroll
  for (int k0=0;k0<U_;k0+=32){
    bf8v a = *reinterpret_cast<const bf8v*>(op + k0);
    #pragma unroll
    for (int nc=0;nc<8;nc++){
      bf8v bb = *reinterpret_cast<const bf8v*>(Wot + (size_t)(n0+nc*16+lq)*U_ + k0 + g*8);
      acc[nc] = MFMA16(a, bb, acc[nc]);
    }
  }

  #pragma unroll
  for (int nc=0;nc<8;nc++){
    int col = n0 + nc*16 + lq;
    float bias = bo[col];
    #pragma unroll
    for (int r=0;r<4;r++){
      int row = m0 + g*4 + r;
      Y[(size_t)row*D_ + col] = acc[nc][r] + bias + X[(size_t)row*D_ + col];
    }
  }
}

extern "C" void kernel_launch(void* const* d_in, const int* in_sizes, int n_in,
                              void* d_out, int out_size, void* d_ws, size_t ws_size,
                              hipStream_t stream) {
  (void)in_sizes; (void)n_in; (void)out_size;
  const float* X  = (const float*)d_in[0];
  const float* Wq = (const float*)d_in[1];
  const float* Wk = (const float*)d_in[2];
  const float* Wv = (const float*)d_in[3];
  const float* Wo = (const float*)d_in[4];
  const float* bo = (const float*)d_in[5];
  float* Y = (float*)d_out;

  const size_t MB = 1u<<20;
  int nsplit = (ws_size >= 34340864u) ? 4 : ((ws_size >= 30015488u) ? 3 : 2);

  char* ws = (char*)d_ws;
  bf16* Opart = (bf16*)ws;                       // nsplit*4MB
  size_t off = (size_t)nsplit*4*MB;
  bf16* Qb  = (bf16*)(ws + off); off += 4*MB;
  bf16* Kb  = (bf16*)(ws + off); off += 4*MB;
  bf16* Vt  = (bf16*)(ws + off); off += 4*MB;
  bf16* Ob  = (bf16*)(ws + off); off += 4*MB;
  bf16* Wqt = (bf16*)(ws + off); off += 65536;
  bf16* Wkt = (bf16*)(ws + off); off += 65536;
  bf16* Wvt = (bf16*)(ws + off); off += 65536;
  bf16* Wot = (bf16*)(ws + off); off += 65536;
  float* Mst = (float*)(ws + off); off += (size_t)nsplit*BS_*4;
  float* Lst = (float*)(ws + off);

  prep_w_kernel<<<dim3(512), dim3(256), 0, stream>>>(Wq, Wk, Wv, Wo, Wqt, Wkt, Wvt, Wot);
  qkv_kernel<<<dim3(BS_/64, 3), dim3(256), 0, stream>>>(X, Wqt, Wkt, Wvt, Qb, Kb, Vt);
  flash_kernel<<<dim3(16*nsplit*8), dim3(256), 0, stream>>>(Qb, Kb, Vt, Opart, Mst, Lst, nsplit);
  combine_kernel<<<dim3(BS_*U_/8/256), dim3(256), 0, stream>>>(Opart, Mst, Lst, Ob, nsplit);
  oproj_kernel<<<dim3(BS_/64, 2), dim3(256), 0, stream>>>(Ob, Wot, X, bo, Y);
}

// Round 10
// 94.530 us; speedup vs baseline: 1.4725x; 1.0240x over previous
//
#include <hip/hip_runtime.h>
#include <hip/hip_bf16.h>

#define B_ 8
#define S_ 2048
#define D_ 256
#define U_ 128
#define BS_ (B_*S_)

using bf16 = __hip_bfloat16;
typedef __attribute__((ext_vector_type(8))) __bf16 bf8v;      // MFMA A/B frag (4 VGPR)
typedef __attribute__((ext_vector_type(4))) float f4v;        // 16x16 C/D frag
typedef __attribute__((ext_vector_type(16))) float f16v;      // 32x32 C/D frag
typedef __attribute__((ext_vector_type(4))) float float4v;
typedef __attribute__((ext_vector_type(4))) unsigned short us4;
typedef __attribute__((ext_vector_type(8))) unsigned short us8;
typedef __attribute__((ext_vector_type(4))) unsigned int u4v;
typedef __attribute__((ext_vector_type(2))) unsigned int u2v;

#define MFMA16(a,b,c) __builtin_amdgcn_mfma_f32_16x16x32_bf16((a),(b),(c),0,0,0)
#define MFMA32(a,b,c) __builtin_amdgcn_mfma_f32_32x32x16_bf16((a),(b),(c),0,0,0)

#if __has_builtin(__builtin_amdgcn_exp2f)
#define EXP2(x) __builtin_amdgcn_exp2f(x)
#else
#define EXP2(x) exp2f(x)
#endif

__device__ __forceinline__ unsigned short f2bits(float f){
  return __builtin_bit_cast(unsigned short, __float2bfloat16(f));
}
__device__ __forceinline__ float b2f(unsigned short u){
  return __builtin_bit_cast(float, ((unsigned)u) << 16);
}

// permlane32_swap (SSA builtin -> no register-aliasing hazard)
__device__ __forceinline__ void plswap(unsigned &a, unsigned &b){
#if __has_builtin(__builtin_amdgcn_permlane32_swap)
  u2v r = __builtin_amdgcn_permlane32_swap(a, b, 0, 0);
  a = r[0]; b = r[1];
#else
  unsigned as = (unsigned)__shfl_xor((int)a, 32);
  unsigned bs = (unsigned)__shfl_xor((int)b, 32);
  bool hi = (threadIdx.x & 32) != 0;
  unsigned na = hi ? bs : a;
  unsigned nb = hi ? b  : as;
  a = na; b = nb;
#endif
}
__device__ __forceinline__ float cross_max(float x){
  unsigned a = __builtin_bit_cast(unsigned, x), b = a;
  plswap(a, b);
  return fmaxf(__builtin_bit_cast(float, a), __builtin_bit_cast(float, b));
}
__device__ __forceinline__ float cross_sum(float x){
  unsigned a = __builtin_bit_cast(unsigned, x), b = a;
  plswap(a, b);
  return __builtin_bit_cast(float, a) + __builtin_bit_cast(float, b);
}

// async global->LDS, 16B per lane; LDS dest = wave-uniform base + lane*16
__device__ __forceinline__ void gload16(const void* g, void* l){
  __builtin_amdgcn_global_load_lds(
    (const __attribute__((address_space(1))) char*)(unsigned long long)g,
    (__attribute__((address_space(3))) char*)(unsigned int)(unsigned long long)l,
    16, 0, 0);
}

// ---------------- prep: weight transpose+convert ----------------
__global__ __launch_bounds__(256) void prep_w_kernel(const float* __restrict__ Wq,
                                                     const float* __restrict__ Wk,
                                                     const float* __restrict__ Wv,
                                                     const float* __restrict__ Wo,
                                                     bf16* __restrict__ Wqt,
                                                     bf16* __restrict__ Wkt,
                                                     bf16* __restrict__ Wvt,
                                                     bf16* __restrict__ Wot){
  int t = blockIdx.x*256 + threadIdx.x;             // 4*32768 threads
  int s = t >> 15;
  int idx = t & 32767;
  if (s < 3){
    const float* src = (s==0)?Wq:((s==1)?Wk:Wv);
    bf16* dst = (s==0)?Wqt:((s==1)?Wkt:Wvt);
    int u = idx >> 8;          // /D_ = 256
    int d = idx & 255;
    dst[(size_t)u*D_ + d] = __float2bfloat16(src[(size_t)d*U_ + u]);
  } else {
    int dd = idx >> 7;         // /U_ = 128
    int u  = idx & 127;
    Wot[(size_t)dd*U_ + u] = __float2bfloat16(Wo[(size_t)u*D_ + dd]);
  }
}

// ---------------- QKV projection GEMM (reads X fp32, converts inline) ----------------
// Q is pre-scaled by log2(e)/sqrt(U) so softmax can use native exp2.
__global__ __launch_bounds__(256) void qkv_kernel(const float* __restrict__ X,
                                                  const bf16* __restrict__ Wqt,
                                                  const bf16* __restrict__ Wkt,
                                                  const bf16* __restrict__ Wvt,
                                                  bf16* __restrict__ Q,
                                                  bf16* __restrict__ K,
                                                  bf16* __restrict__ Vt){
  const int which = blockIdx.y;
  const bf16* Wt = (which==0) ? Wqt : ((which==1) ? Wkt : Wvt);
  const int w    = threadIdx.x >> 6;
  const int lane = threadIdx.x & 63;
  const int lq   = lane & 15;
  const int g    = lane >> 4;
  const int m0   = blockIdx.x*64 + w*16;

  f4v acc[8];
  #pragma unroll
  for (int i=0;i<8;i++) acc[i] = (f4v){0.f,0.f,0.f,0.f};

  const float* xp = X + (size_t)(m0+lq)*D_ + g*8;
  #pragma unroll
  for (int k0=0;k0<D_;k0+=32){
    float4v x0 = *reinterpret_cast<const float4v*>(xp + k0);
    float4v x1 = *reinterpret_cast<const float4v*>(xp + k0 + 4);
    us8 av;
    #pragma unroll
    for (int j=0;j<4;j++){ av[j] = f2bits(x0[j]); av[4+j] = f2bits(x1[j]); }
    bf8v a = __builtin_bit_cast(bf8v, av);
    #pragma unroll
    for (int nc=0;nc<8;nc++){
      bf8v b = *reinterpret_cast<const bf8v*>(Wt + (size_t)(nc*16+lq)*D_ + k0 + g*8);
      acc[nc] = MFMA16(a, b, acc[nc]);
    }
  }

  if (which==0){
    const float qscale = 0.12751745562008530f;      // log2(e)/sqrt(U)
    #pragma unroll
    for (int nc=0;nc<8;nc++){
      #pragma unroll
      for (int r=0;r<4;r++){
        Q[(size_t)(m0+g*4+r)*U_ + nc*16+lq] = __float2bfloat16(acc[nc][r]*qscale);
      }
    }
  } else if (which==1){
    #pragma unroll
    for (int nc=0;nc<8;nc++){
      #pragma unroll
      for (int r=0;r<4;r++){
        K[(size_t)(m0+g*4+r)*U_ + nc*16+lq] = __float2bfloat16(acc[nc][r]);
      }
    }
  } else {
    #pragma unroll
    for (int nc=0;nc<8;nc++){
      #pragma unroll
      for (int r=0;r<4;r++){
        int m = m0 + g*4 + r;
        int b = m >> 11;               // /S_
        int s = m & (S_-1);
        Vt[((size_t)b*U_ + nc*16+lq)*S_ + s] = __float2bfloat16(acc[nc][r]);
      }
    }
  }
}

// ---------------- flash attention: K+V LDS-staged, subtile-pipelined, 32x32 MFMA ----------------
// grid = 16*nsplit*8 blocks x 256 thr (4 waves). blockIdx.x = (qt*nsplit+s)*8 + b.
// Each wave owns a different 32-q tile; 4 waves share staged K+V streams.
// Per 64-k tile: compute BOTH subtiles' QK^T first (stA, stB), then
// softmax(A)+PV(A), softmax(B)+PV(B) -> softmax VALU overlaps MFMA in the wave.
__global__ __launch_bounds__(256) void flash_kernel(const bf16* __restrict__ Q,
                                                    const bf16* __restrict__ K,
                                                    const bf16* __restrict__ Vt,
                                                    bf16* __restrict__ Opart,
                                                    float* __restrict__ Mst,
                                                    float* __restrict__ Lst,
                                                    int nsplit){
  __shared__ bf16 Kls[2][64*128];      // 2 x 16KB
  __shared__ bf16 Vls[2][128*64];      // 2 x 16KB

  const int n    = blockIdx.x;
  const int b    = n & 7;
  const int m    = n >> 3;
  const int s    = m % nsplit;
  const int qt   = m / nsplit;
  const int w    = threadIdx.x >> 6;
  const int lane = threadIdx.x & 63;
  const int l5   = lane & 31;
  const int hi   = lane >> 5;
  const int q0   = qt*128 + w*32;

  const int NT = S_/64;                // 32 big tiles
  const int t0 = (s*NT)/nsplit;
  const int t1 = ((s+1)*NT)/nsplit;

  // Q B-frags (pre-scaled): lane holds Q[q0+l5][uc*16 + hi*8 + j]
  const bf16* Qp = Q + (size_t)(b*S_ + q0 + l5)*U_ + hi*8;
  bf8v qf[8];
  #pragma unroll
  for (int uc=0; uc<8; uc++) qf[uc] = *reinterpret_cast<const bf8v*>(Qp + uc*16);

  f16v o[4];
  #pragma unroll
  for (int uc=0; uc<4; uc++)
    #pragma unroll
    for (int r=0; r<16; r++) o[uc][r] = 0.f;

  float mrow = -1e30f, lrow = 0.f;

  const bf16* Kbase = K  + (size_t)b*S_*U_;
  const bf16* Vtb   = Vt + (size_t)b*U_*S_;     // row u, stride S_

  // stage K tile t (rows = k, 256B each): wave w covers k-rows [w*16, w*16+16)
  auto stageK = [&](int buf, int t){
    const int r0 = w*16;
    #pragma unroll
    for (int c=0; c<4; c++){
      int row  = r0 + c*4 + (lane>>4);
      int soff = ((lane&15)<<4) ^ ((row&7)<<4);
      const char* src = (const char*)(Kbase + (size_t)(t*64 + row)*U_) + soff;
      gload16(src, (void*)&Kls[buf][(r0 + c*4)*128]);
    }
  };
  // stage V tile t (rows = u, 128B each = 64 k): wave w covers u-rows [w*32, w*32+32)
  auto stageV = [&](int buf, int t){
    const int r0 = w*32;
    #pragma unroll
    for (int c=0; c<4; c++){
      int u    = r0 + c*8 + (lane>>3);
      int soff = ((lane&7)<<4) ^ ((u&7)<<4);
      const char* src = (const char*)(Vtb + (size_t)u*S_ + t*64) + soff;
      gload16(src, (void*)&Vls[buf][(r0 + c*8)*64]);
    }
  };

  // softmax + P-pack + PV for one 32-k subtile held in st
  auto process = [&](f16v &st, const char* vb0, int sub){
    float p[16];
    #pragma unroll
    for (int r=0;r<16;r++) p[r] = st[r];

    float a0 = fmaxf(p[0],p[1]),  a1 = fmaxf(p[2],p[3]);
    float a2 = fmaxf(p[4],p[5]),  a3 = fmaxf(p[6],p[7]);
    float a4 = fmaxf(p[8],p[9]),  a5 = fmaxf(p[10],p[11]);
    float a6 = fmaxf(p[12],p[13]),a7 = fmaxf(p[14],p[15]);
    float b0 = fmaxf(a0,a1), b1 = fmaxf(a2,a3), b2 = fmaxf(a4,a5), b3 = fmaxf(a6,a7);
    float tm = fmaxf(fmaxf(b0,b1), fmaxf(b2,b3));
    tm = cross_max(tm);

    if (!__all(tm <= mrow + 11.54f)){        // defer-max (8 nats in log2)
      float mn    = fmaxf(mrow, tm);
      float alpha = EXP2(mrow - mn);
      lrow *= alpha;
      #pragma unroll
      for (int uc=0;uc<4;uc++)
        #pragma unroll
        for (int r=0;r<16;r++) o[uc][r] *= alpha;
      mrow = mn;
    }

    #pragma unroll
    for (int r=0;r<16;r++) p[r] = EXP2(p[r]-mrow);
    float s0s = (p[0]+p[1]) + (p[2]+p[3]);
    float s1s = (p[4]+p[5]) + (p[6]+p[7]);
    float s2s = (p[8]+p[9]) + (p[10]+p[11]);
    float s3s = (p[12]+p[13]) + (p[14]+p[15]);
    lrow += cross_sum((s0s+s1s) + (s2s+s3s));

    unsigned c0 = (unsigned)f2bits(p[0])  | ((unsigned)f2bits(p[1])<<16);
    unsigned c1 = (unsigned)f2bits(p[2])  | ((unsigned)f2bits(p[3])<<16);
    unsigned c2 = (unsigned)f2bits(p[4])  | ((unsigned)f2bits(p[5])<<16);
    unsigned c3 = (unsigned)f2bits(p[6])  | ((unsigned)f2bits(p[7])<<16);
    unsigned c4 = (unsigned)f2bits(p[8])  | ((unsigned)f2bits(p[9])<<16);
    unsigned c5 = (unsigned)f2bits(p[10]) | ((unsigned)f2bits(p[11])<<16);
    unsigned c6 = (unsigned)f2bits(p[12]) | ((unsigned)f2bits(p[13])<<16);
    unsigned c7 = (unsigned)f2bits(p[14]) | ((unsigned)f2bits(p[15])<<16);
    plswap(c0, c2);
    plswap(c1, c3);
    plswap(c4, c6);
    plswap(c5, c7);
    u4v w0v = {c0, c1, c2, c3};
    u4v w1v = {c4, c5, c6, c7};
    bf8v pa0 = __builtin_bit_cast(bf8v, w0v);   // P[q=l5][k = hi*8+j]
    bf8v pa1 = __builtin_bit_cast(bf8v, w1v);   // P[q=l5][k = 16+hi*8+j]

    __builtin_amdgcn_s_setprio(1);
    #pragma unroll
    for (int uc=0; uc<4; uc++){
      const char* vrow = vb0 + (uc*32 + l5)*128;
      bf8v v0 = *reinterpret_cast<const bf8v*>(vrow + ((sub*64      + hi*16) ^ ((l5&7)<<4)));
      bf8v v1 = *reinterpret_cast<const bf8v*>(vrow + ((sub*64 + 32 + hi*16) ^ ((l5&7)<<4)));
      o[uc] = MFMA32(v0, pa0, o[uc]);
      o[uc] = MFMA32(v1, pa1, o[uc]);
    }
    __builtin_amdgcn_s_setprio(0);
  };

  stageK(0, t0); stageV(0, t0);
  int cur = 0;
  for (int tt=t0; tt<t1; ++tt){
    int tn = (tt+1 < NT) ? (tt+1) : (NT-1);
    stageK(cur^1, tn); stageV(cur^1, tn);              // 8 vmem in flight for t+1
    asm volatile("s_waitcnt vmcnt(8)" ::: "memory");   // tile tt fully staged
    __builtin_amdgcn_s_barrier();
    unsigned bufoff = (unsigned)cur * 16384u;          // launder: pin LDS reads after barrier
    asm volatile("" : "+v"(bufoff) : : "memory");
    const char* kb0 = (const char*)&Kls[0][0] + bufoff;
    const char* vb0 = (const char*)&Vls[0][0] + bufoff;

    // ---- QK^T for BOTH subtiles up front (pipelines MFMA under later VALU) ----
    f16v stA, stB;
    #pragma unroll
    for (int r=0;r<16;r++){ stA[r]=0.f; stB[r]=0.f; }
    __builtin_amdgcn_s_setprio(1);
    #pragma unroll
    for (int uc=0; uc<4; uc++){
      bf8v ka = *reinterpret_cast<const bf8v*>(kb0 + l5*256 + ((uc*64      + hi*16) ^ ((l5&7)<<4)));
      bf8v kc = *reinterpret_cast<const bf8v*>(kb0 + l5*256 + ((uc*64 + 32 + hi*16) ^ ((l5&7)<<4)));
      stA = MFMA32(ka, qf[2*uc],   stA);
      stA = MFMA32(kc, qf[2*uc+1], stA);
    }
    #pragma unroll
    for (int uc=0; uc<4; uc++){
      bf8v ka = *reinterpret_cast<const bf8v*>(kb0 + 8192 + l5*256 + ((uc*64      + hi*16) ^ ((l5&7)<<4)));
      bf8v kc = *reinterpret_cast<const bf8v*>(kb0 + 8192 + l5*256 + ((uc*64 + 32 + hi*16) ^ ((l5&7)<<4)));
      stB = MFMA32(ka, qf[2*uc],   stB);
      stB = MFMA32(kc, qf[2*uc+1], stB);
    }
    __builtin_amdgcn_s_setprio(0);

    process(stA, vb0, 0);     // softmax-A VALU overlaps stB MFMA tail
    process(stB, vb0, 1);     // softmax-B VALU overlaps PV-A MFMA

    asm volatile("" ::: "memory");
    __builtin_amdgcn_s_barrier();    // all waves done reading buffers before restage
    cur ^= 1;
  }

  // ---- epilogue: per-wave (q-rows disjoint) normalized partial + stats ----
  const size_t rowg = (size_t)(b*S_ + q0 + l5);
  if (hi==0){
    Mst[(size_t)s*BS_ + rowg] = mrow;
    Lst[(size_t)s*BS_ + rowg] = lrow;
  }
  float inv = 1.0f / lrow;
  bf16* Op = Opart + (size_t)s*BS_*U_ + rowg*U_;
  #pragma unroll
  for (int uc=0; uc<4; uc++){
    #pragma unroll
    for (int g2=0; g2<4; g2++){
      us4 outv;
      #pragma unroll
      for (int j=0;j<4;j++) outv[j] = f2bits(o[uc][g2*4+j]*inv);
      *reinterpret_cast<us4*>(Op + uc*32 + g2*8 + hi*4) = outv;
    }
  }
}

// ---------------- combine the KV splits (log2-domain stats) ----------------
__global__ __launch_bounds__(256) void combine_kernel(const bf16* __restrict__ Opart,
                                                      const float* __restrict__ Mst,
                                                      const float* __restrict__ Lst,
                                                      bf16* __restrict__ O,
                                                      int nsplit){
  int idx = blockIdx.x*256 + threadIdx.x;   // BS*U/8 threads
  int row = idx >> 4;
  int uc8 = (idx & 15) * 8;
  float m0 = Mst[row];
  float m1 = (nsplit>1) ? Mst[BS_+row]   : -1e30f;
  float m2 = (nsplit>2) ? Mst[2*BS_+row] : -1e30f;
  float m3 = (nsplit>3) ? Mst[3*BS_+row] : -1e30f;
  float M  = fmaxf(fmaxf(m0,m1), fmaxf(m2,m3));
  float w0 = Lst[row]*EXP2(m0-M);
  float w1 = (nsplit>1) ? Lst[BS_+row]*EXP2(m1-M)   : 0.f;
  float w2 = (nsplit>2) ? Lst[2*BS_+row]*EXP2(m2-M) : 0.f;
  float w3 = (nsplit>3) ? Lst[3*BS_+row]*EXP2(m3-M) : 0.f;
  float inv = 1.0f/(w0+w1+w2+w3);
  const size_t off = (size_t)row*U_ + uc8;
  const unsigned short* Ou = reinterpret_cast<const unsigned short*>(Opart);
  float acc[8];
  us8 p0 = *reinterpret_cast<const us8*>(Ou + off);
  #pragma unroll
  for (int j=0;j<8;j++) acc[j] = w0*b2f(p0[j]);
  if (nsplit>1){
    us8 p1 = *reinterpret_cast<const us8*>(Ou + (size_t)BS_*U_ + off);
    #pragma unroll
    for (int j=0;j<8;j++) acc[j] += w1*b2f(p1[j]);
  }
  if (nsplit>2){
    us8 p2 = *reinterpret_cast<const us8*>(Ou + (size_t)2*BS_*U_ + off);
    #pragma unroll
    for (int j=0;j<8;j++) acc[j] += w2*b2f(p2[j]);
  }
  if (nsplit>3){
    us8 p3 = *reinterpret_cast<const us8*>(Ou + (size_t)3*BS_*U_ + off);
    #pragma unroll
    for (int j=0;j<8;j++) acc[j] += w3*b2f(p3[j]);
  }
  us8 outv;
  #pragma unroll
  for (int j=0;j<8;j++) outv[j] = f2bits(acc[j]*inv);
  *reinterpret_cast<us8*>(reinterpret_cast<unsigned short*>(O) + off) = outv;
}

// ---------------- output projection + residual ----------------
__global__ __launch_bounds__(256) void oproj_kernel(const bf16* __restrict__ O,
                                                    const bf16* __restrict__ Wot,
                                                    const float* __restrict__ X,
                                                    const float* __restrict__ bo,
                                                    float* __restrict__ Y){
  const int w    = threadIdx.x >> 6;
  const int lane = threadIdx.x & 63;
  const int lq   = lane & 15;
  const int g    = lane >> 4;
  const int m0   = blockIdx.x*64 + w*16;
  const int n0   = blockIdx.y*128;

  f4v acc[8];
  #pragma unroll
  for (int i=0;i<8;i++) acc[i] = (f4v){0.f,0.f,0.f,0.f};

  const bf16* op = O + (size_t)(m0+lq)*U_ + g*8;
  #pragma unroll
  for (int k0=0;k0<U_;k0+=32){
    bf8v a = *reinterpret_cast<const bf8v*>(op + k0);
    #pragma unroll
    for (int nc=0;nc<8;nc++){
      bf8v bb = *reinterpret_cast<const bf8v*>(Wot + (size_t)(n0+nc*16+lq)*U_ + k0 + g*8);
      acc[nc] = MFMA16(a, bb, acc[nc]);
    }
  }

  #pragma unroll
  for (int nc=0;nc<8;nc++){
    int col = n0 + nc*16 + lq;
    float bias = bo[col];
    #pragma unroll
    for (int r=0;r<4;r++){
      int row = m0 + g*4 + r;
      Y[(size_t)row*D_ + col] = acc[nc][r] + bias + X[(size_t)row*D_ + col];
    }
  }
}

extern "C" void kernel_launch(void* const* d_in, const int* in_sizes, int n_in,
                              void* d_out, int out_size, void* d_ws, size_t ws_size,
                              hipStream_t stream) {
  (void)in_sizes; (void)n_in; (void)out_size;
  const float* X  = (const float*)d_in[0];
  const float* Wq = (const float*)d_in[1];
  const float* Wk = (const float*)d_in[2];
  const float* Wv = (const float*)d_in[3];
  const float* Wo = (const float*)d_in[4];
  const float* bo = (const float*)d_in[5];
  float* Y = (float*)d_out;

  const size_t MB = 1u<<20;
  int nsplit = (ws_size >= 34340864u) ? 4 : ((ws_size >= 30015488u) ? 3 : 2);

  char* ws = (char*)d_ws;
  bf16* Opart = (bf16*)ws;                       // nsplit*4MB
  size_t off = (size_t)nsplit*4*MB;
  bf16* Qb  = (bf16*)(ws + off); off += 4*MB;
  bf16* Kb  = (bf16*)(ws + off); off += 4*MB;
  bf16* Vt  = (bf16*)(ws + off); off += 4*MB;
  bf16* Ob  = (bf16*)(ws + off); off += 4*MB;
  bf16* Wqt = (bf16*)(ws + off); off += 65536;
  bf16* Wkt = (bf16*)(ws + off); off += 65536;
  bf16* Wvt = (bf16*)(ws + off); off += 65536;
  bf16* Wot = (bf16*)(ws + off); off += 65536;
  float* Mst = (float*)(ws + off); off += (size_t)nsplit*BS_*4;
  float* Lst = (float*)(ws + off);

  prep_w_kernel<<<dim3(512), dim3(256), 0, stream>>>(Wq, Wk, Wv, Wo, Wqt, Wkt, Wvt, Wot);
  qkv_kernel<<<dim3(BS_/64, 3), dim3(256), 0, stream>>>(X, Wqt, Wkt, Wvt, Qb, Kb, Vt);
  flash_kernel<<<dim3(16*nsplit*8), dim3(256), 0, stream>>>(Qb, Kb, Vt, Opart, Mst, Lst, nsplit);
  combine_kernel<<<dim3(BS_*U_/8/256), dim3(256), 0, stream>>>(Opart, Mst, Lst, Ob, nsplit);
  oproj_kernel<<<dim3(BS_/64, 2), dim3(256), 0, stream>>>(Ob, Wot, X, bo, Y);
}